// Round 6
// baseline (4222.616 us; speedup 1.0000x reference)
//
#include <hip/hip_runtime.h>
#include <stdint.h>

// ---------------------------------------------------------------------------
// Critic: encoder -> 255-step LSTM (U=256, D_in=256) -> 1-unit relu head. B=512
//
// Round-9 design:
//  - REVERT round-7's ring cap (producer throttling cost 2.2x; FETCH showed
//    z reads were already cache-served). Ring is again sized to fill the
//    workspace -> producers sprint ahead, never on the critical path.
//  - NEW: depth-2 z prefetch (RS>=4 path): z(s+2) issued at step s into the
//    register set freed by consuming z(s) (even/odd parity, no dyn indexing).
//    ~2 full steps of cover for every z load. Fallback = round-8 depth-1
//    loop (verified) for RS<4.
//  - lgkm-only recurrence barrier, resident weights (6 reg + 2 LDS tiles
//    per wave), window handshake, producers: unchanged.
// ---------------------------------------------------------------------------

#define NSTEP 255

typedef __attribute__((ext_vector_type(8))) short short8;   // 8 x bf16
typedef __attribute__((ext_vector_type(4))) float f32x4;

#define HSTR 280   // hbuf row stride in shorts (560 B, 16B-aligned)

__device__ __forceinline__ unsigned short f2bf(float f) {
    union { float f; unsigned int u; } v; v.f = f;
    unsigned int r = v.u + 0x7FFFu + ((v.u >> 16) & 1u);   // RNE
    return (unsigned short)(r >> 16);
}
__device__ __forceinline__ float fexp2(float x) { return __builtin_amdgcn_exp2f(x); }
__device__ __forceinline__ float frcp(float x)  { return __builtin_amdgcn_rcpf(x); }
__device__ __forceinline__ float sigm(float x)  { return frcp(1.0f + fexp2(-1.44269504f * x)); }
__device__ __forceinline__ float tanh_(float x) { return 1.0f - 2.0f * frcp(1.0f + fexp2(2.88539008f * x)); }

// ---------------------------------------------------------------------------
// Encoder: state = relu(concat(ms,rs,re,im) @ Wc + bc)   [512,256] fp32
// ---------------------------------------------------------------------------
__global__ __launch_bounds__(256)
void encoder_kernel(const float* __restrict__ motion, const float* __restrict__ robot,
                    const float* __restrict__ osr, const float* __restrict__ osi,
                    const float* __restrict__ ore, const float* __restrict__ oie,
                    const float* __restrict__ Wm, const float* __restrict__ bm,
                    const float* __restrict__ Wr, const float* __restrict__ br,
                    const float* __restrict__ Wre, const float* __restrict__ bre,
                    const float* __restrict__ Wim, const float* __restrict__ bim,
                    const float* __restrict__ Wc, const float* __restrict__ bc,
                    float* __restrict__ state)
{
    __shared__ float in_m[16][64];
    __shared__ float in_r[16][128];
    __shared__ float in_re[16][128];
    __shared__ float in_im[16][128];
    __shared__ float catb[16 * 768];
    const int t = threadIdx.x;
    const int m0 = blockIdx.x * 16;

    {
        int idx = t * 4; int row = idx >> 6, col = idx & 63;
        *(float4*)&in_m[row][col]       = *(const float4*)(motion + (m0 + row) * 64 + col);
        *(float4*)&in_re[row][col]      = *(const float4*)(osr + (m0 + row) * 64 + col);
        *(float4*)&in_re[row][64 + col] = *(const float4*)(ore + (m0 + row) * 64 + col);
        *(float4*)&in_im[row][col]      = *(const float4*)(osi + (m0 + row) * 64 + col);
        *(float4*)&in_im[row][64 + col] = *(const float4*)(oie + (m0 + row) * 64 + col);
    }
    for (int p = 0; p < 2; ++p) {
        int idx = (t + p * 256) * 4; int row = idx >> 7, col = idx & 127;
        *(float4*)&in_r[row][col] = *(const float4*)(robot + (m0 + row) * 128 + col);
    }
    __syncthreads();

    for (int row = 0; row < 16; ++row) {
        {
            float s = bm[t];
            for (int k = 0; k < 64; ++k) s += in_m[row][k] * Wm[k * 256 + t];
            catb[row * 768 + t] = fmaxf(s, 0.0f);
        }
        {
            float s = br[t];
            for (int k = 0; k < 128; ++k) s += in_r[row][k] * Wr[k * 256 + t];
            catb[row * 768 + 256 + t] = fmaxf(s, 0.0f);
        }
        if (t < 128) {
            float s = bre[t];
            for (int k = 0; k < 128; ++k) s += in_re[row][k] * Wre[k * 128 + t];
            catb[row * 768 + 512 + t] = fmaxf(s, 0.0f);
        } else {
            const int u = t - 128;
            float s = bim[u];
            for (int k = 0; k < 128; ++k) s += in_im[row][k] * Wim[k * 128 + u];
            catb[row * 768 + 640 + u] = fmaxf(s, 0.0f);
        }
    }
    __syncthreads();

    for (int r0 = 0; r0 < 16; r0 += 4) {
        float a0 = bc[t], a1 = bc[t], a2 = bc[t], a3 = bc[t];
        for (int j = 0; j < 768; ++j) {
            const float wv = Wc[j * 256 + t];
            a0 += catb[(r0 + 0) * 768 + j] * wv;
            a1 += catb[(r0 + 1) * 768 + j] * wv;
            a2 += catb[(r0 + 2) * 768 + j] * wv;
            a3 += catb[(r0 + 3) * 768 + j] * wv;
        }
        state[(m0 + r0 + 0) * 256 + t] = fmaxf(a0, 0.0f);
        state[(m0 + r0 + 1) * 256 + t] = fmaxf(a1, 0.0f);
        state[(m0 + r0 + 2) * 256 + t] = fmaxf(a2, 0.0f);
        state[(m0 + r0 + 3) * 256 + t] = fmaxf(a3, 0.0f);
    }
}

// ---------------------------------------------------------------------------
// Prep: W2k/W2r in frag-linear layout [(T*8+kk)*64+lane][8], bf16.
// ---------------------------------------------------------------------------
__global__ __launch_bounds__(256)
void prep_kernel(const float* __restrict__ Wk, const float* __restrict__ Wrk,
                 const float* __restrict__ bl,
                 unsigned short* __restrict__ W2k, unsigned short* __restrict__ W2r,
                 float* __restrict__ blr2,
                 unsigned int* __restrict__ prod_flag, unsigned int* __restrict__ cons_prog)
{
    const int blk = blockIdx.x, t = threadIdx.x;
    if (blk < 256) {
        const int mat = blk >> 7;
        const int idx = (blk & 127) * 256 + t;      // (T*8+kk)*64+lane
        const int T = idx >> 9, kk = (idx >> 6) & 7, lane = idx & 63;
        const int q = lane >> 4, cid = lane & 15;
        const int wv = T >> 4, gam = (T >> 2) & 3, g = T & 3;
        const int col = g * 256 + wv * 64 + gam * 16 + cid;
        const float* W = mat ? Wrk : Wk;
        unsigned short* O = mat ? W2r : W2k;
#pragma unroll
        for (int j = 0; j < 8; ++j) {
            const int k = kk * 32 + q * 8 + j;
            O[(size_t)idx * 8 + j] = f2bf(W[(size_t)k * 1024 + col]);
        }
    } else {
        for (int e = t; e < 4096; e += 256) {
            const int T = e >> 6, lane = e & 63, cid = lane & 15;
            const int wv = T >> 4, gam = (T >> 2) & 3, g = T & 3;
            blr2[e] = bl[g * 256 + wv * 64 + gam * 16 + cid];
        }
        for (int i = t; i < 40960; i += 256) prod_flag[i] = 0u;
        for (int i = t; i < 512; i += 256) cons_prog[i] = 0u;
    }
}

// ---------------------------------------------------------------------------
// Fused: blocks 0..31 = consumers (recurrence, 8 waves), 32..255 = producers.
// z ring is f32 C-fragments: z[(slot*32+m)*16384 + (T*64+lane)*4 .. +3]
// ---------------------------------------------------------------------------
__global__ __launch_bounds__(512, 2)
void fused_kernel(const float* __restrict__ hist, const float* __restrict__ act,
                  const float* __restrict__ state,
                  const unsigned short* __restrict__ W2k, const unsigned short* __restrict__ W2r,
                  const float* __restrict__ blr2,
                  const float* __restrict__ Wo, const float* __restrict__ bo_p,
                  float* __restrict__ zf32, float* __restrict__ hfing,
                  unsigned int* __restrict__ prod_flag, unsigned int* __restrict__ cons_prog,
                  float* __restrict__ out,
                  int WSH, int NW, int RS, int ring_steps)
{
    __shared__ __align__(16) unsigned char smem[148992];
    unsigned short* ldsW = (unsigned short*)smem;                 // 131072 B (2 Wrk tiles / wave)
    unsigned short* hbuf0 = (unsigned short*)(smem + 131072);     // 16*HSTR*2 = 8960 B
    unsigned short* hbuf1 = (unsigned short*)(smem + 140032);     // 8960 B

    const int tid = threadIdx.x;
    const int w = tid >> 6, lane = tid & 63, q = lane >> 4, cid = lane & 15;
    const int bx = blockIdx.x;
    const int WIN = 1 << WSH, WMASK = WIN - 1;

    if (bx < 32) {
        // ======================= CONSUMER =======================
        const int m = bx, m0 = m * 16;
        const int u0 = (w >> 1) * 64 + ((w & 1) * 2 + 0) * 16 + cid;
        const int u1 = u0 + 16;

        // register-resident Wrk: tiles j=0..5
        short8 Wres[6][8];
#pragma unroll
        for (int t = 0; t < 6; ++t) {
#pragma unroll
            for (int kk = 0; kk < 8; ++kk)
                Wres[t][kk] = *(const short8*)(W2r + ((size_t)((w * 8 + t) * 8 + kk) * 64 + lane) * 8);
        }
        // LDS-resident Wrk: tiles j=6,7
#pragma unroll
        for (int tt = 0; tt < 2; ++tt) {
#pragma unroll
            for (int kk = 0; kk < 8; ++kk) {
                short8 f = *(const short8*)(W2r + ((size_t)((w * 8 + 6 + tt) * 8 + kk) * 64 + lane) * 8);
                *(short8*)(ldsW + (((w * 2 + tt) * 8 + kk) * 64 + lane) * 8) = f;
            }
        }
        // h^0 = bf16(state tile)
        {
            const int row = tid >> 5, c0 = (tid & 31) * 8;
            const float* sp = state + (size_t)(m0 + row) * 256 + c0;
            const float4 a = *(const float4*)sp;
            const float4 b = *(const float4*)(sp + 4);
            union { unsigned short us[8]; short8 v; } pk;
            pk.us[0] = f2bf(a.x); pk.us[1] = f2bf(a.y); pk.us[2] = f2bf(a.z); pk.us[3] = f2bf(a.w);
            pk.us[4] = f2bf(b.x); pk.us[5] = f2bf(b.y); pk.us[6] = f2bf(b.z); pk.us[7] = f2bf(b.w);
            *(short8*)(hbuf0 + row * HSTR + c0) = pk.v;
        }
        // c^0
        float cc[8];
#pragma unroll
        for (int h = 0; h < 2; ++h)
#pragma unroll
            for (int r = 0; r < 4; ++r)
                cc[h * 4 + r] = state[(size_t)(m0 + q * 4 + r) * 256 + (h ? u1 : u0)];

        __syncthreads();

        unsigned short* hcur = hbuf0;
        unsigned short* hnxt = hbuf1;
        const float* zbw = zf32 + (size_t)lane * 4 + (size_t)w * 2048;

        if (RS >= 4) {
            // ---------------- depth-2 prefetch path ----------------
            f32x4 z1A[4], z1B[4], z2A[4], z2B[4];

            while (__hip_atomic_load(&prod_flag[m * 4],
                                     __ATOMIC_ACQUIRE, __HIP_MEMORY_SCOPE_AGENT) == 0)
                __builtin_amdgcn_s_sleep(1);
            {
                const float* zb = zbw + (size_t)m * 16384;   // slot 0
#pragma unroll
                for (int g = 0; g < 4; ++g) {
                    z1A[g] = *(const f32x4*)(zb + g * 256);
                    z1B[g] = *(const f32x4*)(zb + 1024 + g * 256);
                }
            }
            if ((1 & WMASK) == 0) {   // WIN==1: step 1 is a new window
                while (__hip_atomic_load(&prod_flag[(1 * 32 + m) * 4],
                                         __ATOMIC_ACQUIRE, __HIP_MEMORY_SCOPE_AGENT) == 0)
                    __builtin_amdgcn_s_sleep(1);
            }
            {
                const float* zb = zbw + ((size_t)1 * 32 + m) * 16384;  // slot 1
#pragma unroll
                for (int g = 0; g < 4; ++g) {
                    z2A[g] = *(const f32x4*)(zb + g * 256);
                    z2B[g] = *(const f32x4*)(zb + 1024 + g * 256);
                }
            }
            int sl = 2;   // slot of next step to load (ring_steps >= 4)

            for (int s = 0; s < NSTEP - 2; s += 2) {
                // ================= even phase: step s (z1) =================
                {
                    f32x4 accA[4], accB[4];
#pragma unroll
                    for (int t = 0; t < 4; ++t) { accA[t] = z1A[t]; accB[t] = z1B[t]; }
                    const unsigned short* hrow = hcur + cid * HSTR + q * 8;

                    __builtin_amdgcn_s_setprio(1);
#pragma unroll
                    for (int kk = 0; kk < 8; ++kk) {
                        const short8 a = *(const short8*)(hrow + kk * 32);
                        accA[0] = __builtin_amdgcn_mfma_f32_16x16x32_bf16(a, Wres[0][kk], accA[0], 0, 0, 0);
                        accA[1] = __builtin_amdgcn_mfma_f32_16x16x32_bf16(a, Wres[1][kk], accA[1], 0, 0, 0);
                        accA[2] = __builtin_amdgcn_mfma_f32_16x16x32_bf16(a, Wres[2][kk], accA[2], 0, 0, 0);
                        accA[3] = __builtin_amdgcn_mfma_f32_16x16x32_bf16(a, Wres[3][kk], accA[3], 0, 0, 0);
                    }
                    __builtin_amdgcn_s_setprio(0);

                    // issue z(s+2) into z1 (freed this phase)
                    {
                        const int t2 = s + 2;
                        if ((t2 & WMASK) == 0) {
                            const int fn = t2 >> WSH;
                            while (__hip_atomic_load(&prod_flag[(fn * 32 + m) * 4],
                                                     __ATOMIC_ACQUIRE, __HIP_MEMORY_SCOPE_AGENT) == 0)
                                __builtin_amdgcn_s_sleep(1);
                        }
                        const float* zbn = zbw + ((size_t)sl * 32 + m) * 16384;
#pragma unroll
                        for (int g = 0; g < 4; ++g) {
                            z1A[g] = *(const f32x4*)(zbn + g * 256);
                            z1B[g] = *(const f32x4*)(zbn + 1024 + g * 256);
                        }
                        sl = (sl + 1 == ring_steps) ? 0 : sl + 1;
                    }

#pragma unroll
                    for (int r = 0; r < 4; ++r) {
                        const float c = sigm(accA[1][r]) * cc[r] + sigm(accA[0][r]) * tanh_(accA[2][r]);
                        cc[r] = c;
                        hnxt[(q * 4 + r) * HSTR + u0] = f2bf(sigm(accA[3][r]) * tanh_(c));
                    }

                    __builtin_amdgcn_s_setprio(1);
#pragma unroll
                    for (int kk = 0; kk < 8; ++kk) {
                        const short8 a = *(const short8*)(hrow + kk * 32);
                        accB[0] = __builtin_amdgcn_mfma_f32_16x16x32_bf16(a, Wres[4][kk], accB[0], 0, 0, 0);
                        accB[1] = __builtin_amdgcn_mfma_f32_16x16x32_bf16(a, Wres[5][kk], accB[1], 0, 0, 0);
                        const short8 b6 = *(const short8*)(ldsW + (((w * 2 + 0) * 8 + kk) * 64 + lane) * 8);
                        accB[2] = __builtin_amdgcn_mfma_f32_16x16x32_bf16(a, b6, accB[2], 0, 0, 0);
                        const short8 b7 = *(const short8*)(ldsW + (((w * 2 + 1) * 8 + kk) * 64 + lane) * 8);
                        accB[3] = __builtin_amdgcn_mfma_f32_16x16x32_bf16(a, b7, accB[3], 0, 0, 0);
                    }
                    __builtin_amdgcn_s_setprio(0);

#pragma unroll
                    for (int r = 0; r < 4; ++r) {
                        const float c = sigm(accB[1][r]) * cc[4 + r] + sigm(accB[0][r]) * tanh_(accB[2][r]);
                        cc[4 + r] = c;
                        hnxt[(q * 4 + r) * HSTR + u1] = f2bf(sigm(accB[3][r]) * tanh_(c));
                    }

                    asm volatile("s_waitcnt lgkmcnt(0)" ::: "memory");
                    __builtin_amdgcn_s_barrier();
                    { unsigned short* t_ = hcur; hcur = hnxt; hnxt = t_; }
                    if (((s + 1) & WMASK) == 0 && tid == 0)
                        __hip_atomic_store(&cons_prog[m * 16], (unsigned)((s + 1) >> WSH),
                                           __ATOMIC_RELEASE, __HIP_MEMORY_SCOPE_AGENT);
                }

                // ================= odd phase: step s+1 (z2) =================
                {
                    f32x4 accA[4], accB[4];
#pragma unroll
                    for (int t = 0; t < 4; ++t) { accA[t] = z2A[t]; accB[t] = z2B[t]; }
                    const unsigned short* hrow = hcur + cid * HSTR + q * 8;

                    __builtin_amdgcn_s_setprio(1);
#pragma unroll
                    for (int kk = 0; kk < 8; ++kk) {
                        const short8 a = *(const short8*)(hrow + kk * 32);
                        accA[0] = __builtin_amdgcn_mfma_f32_16x16x32_bf16(a, Wres[0][kk], accA[0], 0, 0, 0);
                        accA[1] = __builtin_amdgcn_mfma_f32_16x16x32_bf16(a, Wres[1][kk], accA[1], 0, 0, 0);
                        accA[2] = __builtin_amdgcn_mfma_f32_16x16x32_bf16(a, Wres[2][kk], accA[2], 0, 0, 0);
                        accA[3] = __builtin_amdgcn_mfma_f32_16x16x32_bf16(a, Wres[3][kk], accA[3], 0, 0, 0);
                    }
                    __builtin_amdgcn_s_setprio(0);

                    // issue z(s+3) into z2 (freed this phase)
                    {
                        const int t2 = s + 3;
                        if (t2 < NSTEP) {
                            if ((t2 & WMASK) == 0) {
                                const int fn = t2 >> WSH;
                                while (__hip_atomic_load(&prod_flag[(fn * 32 + m) * 4],
                                                         __ATOMIC_ACQUIRE, __HIP_MEMORY_SCOPE_AGENT) == 0)
                                    __builtin_amdgcn_s_sleep(1);
                            }
                            const float* zbn = zbw + ((size_t)sl * 32 + m) * 16384;
#pragma unroll
                            for (int g = 0; g < 4; ++g) {
                                z2A[g] = *(const f32x4*)(zbn + g * 256);
                                z2B[g] = *(const f32x4*)(zbn + 1024 + g * 256);
                            }
                            sl = (sl + 1 == ring_steps) ? 0 : sl + 1;
                        }
                    }

#pragma unroll
                    for (int r = 0; r < 4; ++r) {
                        const float c = sigm(accA[1][r]) * cc[r] + sigm(accA[0][r]) * tanh_(accA[2][r]);
                        cc[r] = c;
                        hnxt[(q * 4 + r) * HSTR + u0] = f2bf(sigm(accA[3][r]) * tanh_(c));
                    }

                    __builtin_amdgcn_s_setprio(1);
#pragma unroll
                    for (int kk = 0; kk < 8; ++kk) {
                        const short8 a = *(const short8*)(hrow + kk * 32);
                        accB[0] = __builtin_amdgcn_mfma_f32_16x16x32_bf16(a, Wres[4][kk], accB[0], 0, 0, 0);
                        accB[1] = __builtin_amdgcn_mfma_f32_16x16x32_bf16(a, Wres[5][kk], accB[1], 0, 0, 0);
                        const short8 b6 = *(const short8*)(ldsW + (((w * 2 + 0) * 8 + kk) * 64 + lane) * 8);
                        accB[2] = __builtin_amdgcn_mfma_f32_16x16x32_bf16(a, b6, accB[2], 0, 0, 0);
                        const short8 b7 = *(const short8*)(ldsW + (((w * 2 + 1) * 8 + kk) * 64 + lane) * 8);
                        accB[3] = __builtin_amdgcn_mfma_f32_16x16x32_bf16(a, b7, accB[3], 0, 0, 0);
                    }
                    __builtin_amdgcn_s_setprio(0);

#pragma unroll
                    for (int r = 0; r < 4; ++r) {
                        const float c = sigm(accB[1][r]) * cc[4 + r] + sigm(accB[0][r]) * tanh_(accB[2][r]);
                        cc[4 + r] = c;
                        hnxt[(q * 4 + r) * HSTR + u1] = f2bf(sigm(accB[3][r]) * tanh_(c));
                    }

                    asm volatile("s_waitcnt lgkmcnt(0)" ::: "memory");
                    __builtin_amdgcn_s_barrier();
                    { unsigned short* t_ = hcur; hcur = hnxt; hnxt = t_; }
                    if (((s + 2) & WMASK) == 0 && tid == 0)
                        __hip_atomic_store(&cons_prog[m * 16], (unsigned)((s + 2) >> WSH),
                                           __ATOMIC_RELEASE, __HIP_MEMORY_SCOPE_AGENT);
                }
            }

            // ================= tail: step 254 (z1, last) =================
            {
                f32x4 accA[4], accB[4];
#pragma unroll
                for (int t = 0; t < 4; ++t) { accA[t] = z1A[t]; accB[t] = z1B[t]; }
                const unsigned short* hrow = hcur + cid * HSTR + q * 8;

                __builtin_amdgcn_s_setprio(1);
#pragma unroll
                for (int kk = 0; kk < 8; ++kk) {
                    const short8 a = *(const short8*)(hrow + kk * 32);
                    accA[0] = __builtin_amdgcn_mfma_f32_16x16x32_bf16(a, Wres[0][kk], accA[0], 0, 0, 0);
                    accA[1] = __builtin_amdgcn_mfma_f32_16x16x32_bf16(a, Wres[1][kk], accA[1], 0, 0, 0);
                    accA[2] = __builtin_amdgcn_mfma_f32_16x16x32_bf16(a, Wres[2][kk], accA[2], 0, 0, 0);
                    accA[3] = __builtin_amdgcn_mfma_f32_16x16x32_bf16(a, Wres[3][kk], accA[3], 0, 0, 0);
                }
#pragma unroll
                for (int kk = 0; kk < 8; ++kk) {
                    const short8 a = *(const short8*)(hrow + kk * 32);
                    accB[0] = __builtin_amdgcn_mfma_f32_16x16x32_bf16(a, Wres[4][kk], accB[0], 0, 0, 0);
                    accB[1] = __builtin_amdgcn_mfma_f32_16x16x32_bf16(a, Wres[5][kk], accB[1], 0, 0, 0);
                    const short8 b6 = *(const short8*)(ldsW + (((w * 2 + 0) * 8 + kk) * 64 + lane) * 8);
                    accB[2] = __builtin_amdgcn_mfma_f32_16x16x32_bf16(a, b6, accB[2], 0, 0, 0);
                    const short8 b7 = *(const short8*)(ldsW + (((w * 2 + 1) * 8 + kk) * 64 + lane) * 8);
                    accB[3] = __builtin_amdgcn_mfma_f32_16x16x32_bf16(a, b7, accB[3], 0, 0, 0);
                }
                __builtin_amdgcn_s_setprio(0);

#pragma unroll
                for (int r = 0; r < 4; ++r) {
                    const float c = sigm(accA[1][r]) * cc[r] + sigm(accA[0][r]) * tanh_(accA[2][r]);
                    hfing[(size_t)(m0 + q * 4 + r) * 256 + u0] = sigm(accA[3][r]) * tanh_(c);
                    const float c2 = sigm(accB[1][r]) * cc[4 + r] + sigm(accB[0][r]) * tanh_(accB[2][r]);
                    hfing[(size_t)(m0 + q * 4 + r) * 256 + u1] = sigm(accB[3][r]) * tanh_(c2);
                }
            }
        } else {
            // ---------------- depth-1 fallback (round-8, verified) ----------------
            int zslot = 0;
            f32x4 zA[4], zB[4];

            while (__hip_atomic_load(&prod_flag[m * 4],
                                     __ATOMIC_ACQUIRE, __HIP_MEMORY_SCOPE_AGENT) == 0)
                __builtin_amdgcn_s_sleep(1);
            {
                const float* zb = zbw + (size_t)m * 16384;
#pragma unroll
                for (int g = 0; g < 4; ++g) {
                    zA[g] = *(const f32x4*)(zb + g * 256);
                    zB[g] = *(const f32x4*)(zb + 1024 + g * 256);
                }
            }

            for (int s = 0; s < NSTEP; ++s) {
                const bool last = (s == NSTEP - 1);

                if (RS < 2 && (s & WMASK) == 0 && s > 0) {
                    const int f = s >> WSH;
                    while (__hip_atomic_load(&prod_flag[(f * 32 + m) * 4],
                                             __ATOMIC_ACQUIRE, __HIP_MEMORY_SCOPE_AGENT) == 0)
                        __builtin_amdgcn_s_sleep(1);
                    const float* zb = zbw + ((size_t)zslot * 32 + m) * 16384;
#pragma unroll
                    for (int g = 0; g < 4; ++g) {
                        zA[g] = *(const f32x4*)(zb + g * 256);
                        zB[g] = *(const f32x4*)(zb + 1024 + g * 256);
                    }
                }

                f32x4 accA[4], accB[4];
#pragma unroll
                for (int t = 0; t < 4; ++t) { accA[t] = zA[t]; accB[t] = zB[t]; }

                const unsigned short* hrow = hcur + cid * HSTR + q * 8;

                __builtin_amdgcn_s_setprio(1);
#pragma unroll
                for (int kk = 0; kk < 8; ++kk) {
                    const short8 a = *(const short8*)(hrow + kk * 32);
                    accA[0] = __builtin_amdgcn_mfma_f32_16x16x32_bf16(a, Wres[0][kk], accA[0], 0, 0, 0);
                    accA[1] = __builtin_amdgcn_mfma_f32_16x16x32_bf16(a, Wres[1][kk], accA[1], 0, 0, 0);
                    accA[2] = __builtin_amdgcn_mfma_f32_16x16x32_bf16(a, Wres[2][kk], accA[2], 0, 0, 0);
                    accA[3] = __builtin_amdgcn_mfma_f32_16x16x32_bf16(a, Wres[3][kk], accA[3], 0, 0, 0);
                }
                __builtin_amdgcn_s_setprio(0);

                const int znext = (zslot + 1 == ring_steps) ? 0 : zslot + 1;
                if (!last) {
                    if (RS >= 2) {
                        if (((s + 1) & WMASK) == 0) {
                            const int fn = (s + 1) >> WSH;
                            while (__hip_atomic_load(&prod_flag[(fn * 32 + m) * 4],
                                                     __ATOMIC_ACQUIRE, __HIP_MEMORY_SCOPE_AGENT) == 0)
                                __builtin_amdgcn_s_sleep(1);
                        }
                        const float* zbn = zbw + ((size_t)znext * 32 + m) * 16384;
#pragma unroll
                        for (int g = 0; g < 4; ++g) {
                            zA[g] = *(const f32x4*)(zbn + g * 256);
                            zB[g] = *(const f32x4*)(zbn + 1024 + g * 256);
                        }
                    } else if (((s + 1) & WMASK) != 0) {
                        const float* zbn = zbw + ((size_t)znext * 32 + m) * 16384;
#pragma unroll
                        for (int g = 0; g < 4; ++g) {
                            zA[g] = *(const f32x4*)(zbn + g * 256);
                            zB[g] = *(const f32x4*)(zbn + 1024 + g * 256);
                        }
                    }
                }

#pragma unroll
                for (int r = 0; r < 4; ++r) {
                    const float c = sigm(accA[1][r]) * cc[r] + sigm(accA[0][r]) * tanh_(accA[2][r]);
                    cc[r] = c;
                    const float hv = sigm(accA[3][r]) * tanh_(c);
                    if (!last) hnxt[(q * 4 + r) * HSTR + u0] = f2bf(hv);
                    else       hfing[(size_t)(m0 + q * 4 + r) * 256 + u0] = hv;
                }

                __builtin_amdgcn_s_setprio(1);
#pragma unroll
                for (int kk = 0; kk < 8; ++kk) {
                    const short8 a = *(const short8*)(hrow + kk * 32);
                    accB[0] = __builtin_amdgcn_mfma_f32_16x16x32_bf16(a, Wres[4][kk], accB[0], 0, 0, 0);
                    accB[1] = __builtin_amdgcn_mfma_f32_16x16x32_bf16(a, Wres[5][kk], accB[1], 0, 0, 0);
                    const short8 b6 = *(const short8*)(ldsW + (((w * 2 + 0) * 8 + kk) * 64 + lane) * 8);
                    accB[2] = __builtin_amdgcn_mfma_f32_16x16x32_bf16(a, b6, accB[2], 0, 0, 0);
                    const short8 b7 = *(const short8*)(ldsW + (((w * 2 + 1) * 8 + kk) * 64 + lane) * 8);
                    accB[3] = __builtin_amdgcn_mfma_f32_16x16x32_bf16(a, b7, accB[3], 0, 0, 0);
                }
                __builtin_amdgcn_s_setprio(0);

#pragma unroll
                for (int r = 0; r < 4; ++r) {
                    const float c = sigm(accB[1][r]) * cc[4 + r] + sigm(accB[0][r]) * tanh_(accB[2][r]);
                    cc[4 + r] = c;
                    const float hv = sigm(accB[3][r]) * tanh_(c);
                    if (!last) hnxt[(q * 4 + r) * HSTR + u1] = f2bf(hv);
                    else       hfing[(size_t)(m0 + q * 4 + r) * 256 + u1] = hv;
                }

                asm volatile("s_waitcnt lgkmcnt(0)" ::: "memory");
                __builtin_amdgcn_s_barrier();

                { unsigned short* t_ = hcur; hcur = hnxt; hnxt = t_; }
                if (((s + 1) & WMASK) == 0 && tid == 0)
                    __hip_atomic_store(&cons_prog[m * 16], (unsigned)((s + 1) >> WSH),
                                       __ATOMIC_RELEASE, __HIP_MEMORY_SCOPE_AGENT);
                zslot = znext;
            }
        }

        __syncthreads();   // full drain before head

        // head: out = relu(h_final @ Wo + bo)
        float* redL = (float*)smem;
        if (tid < 256) {
            const int row = tid >> 4, c16 = tid & 15;
            float part = 0.0f;
#pragma unroll
            for (int j = 0; j < 16; ++j) {
                const int u = c16 + j * 16;
                part += hfing[(size_t)(m0 + row) * 256 + u] * Wo[u];
            }
            redL[row * 16 + c16] = part;
        }
        __syncthreads();
        if (tid < 16) {
            float sum = 0.0f;
#pragma unroll
            for (int j = 0; j < 16; ++j) sum += redL[tid * 16 + j];
            out[m0 + tid] = fmaxf(sum + bo_p[0], 0.0f);
        }
    } else {
        // ======================= PRODUCER =======================
        const int p = bx - 32;
        const int total = NW * 32;
        const int slot0 = w & 3, tchalf = w >> 2;   // 4 step-slots x 2 Tc halves
        for (int tau = p; tau < total; tau += 224) {
            const int w_ = tau >> 5, m = tau & 31, m0 = m * 16;
            const int nst = (WIN < NSTEP - w_ * WIN) ? WIN : (NSTEP - w_ * WIN);
            if (w_ >= RS) {
                const unsigned need = (unsigned)(w_ - RS + 1);
                while (__hip_atomic_load(&cons_prog[m * 16],
                                         __ATOMIC_ACQUIRE, __HIP_MEMORY_SCOPE_AGENT) < need)
                    __builtin_amdgcn_s_sleep(4);
            }
            int ns_my = 0; int sabs[2] = {0, 0};
            for (int sl = slot0; sl < nst; sl += 4) { if (ns_my < 2) sabs[ns_my++] = w_ * WIN + sl; }

            short8 A2[2][8];
#pragma unroll
            for (int si = 0; si < 2; ++si) {
                if (si < ns_my) {
                    const int s = sabs[si];
                    const float* xs = (s < 127)
                        ? hist + ((size_t)(m0 + cid) * 128 + s) * 256
                        : act + ((size_t)(m0 + cid) * 128 + (s - 127)) * 256;
#pragma unroll
                    for (int kk = 0; kk < 8; ++kk) {
                        const float4 a = *(const float4*)(xs + kk * 32 + q * 8);
                        const float4 b = *(const float4*)(xs + kk * 32 + q * 8 + 4);
                        union { unsigned short us[8]; short8 v; } pk;
                        pk.us[0] = f2bf(a.x); pk.us[1] = f2bf(a.y);
                        pk.us[2] = f2bf(a.z); pk.us[3] = f2bf(a.w);
                        pk.us[4] = f2bf(b.x); pk.us[5] = f2bf(b.y);
                        pk.us[6] = f2bf(b.z); pk.us[7] = f2bf(b.w);
                        A2[si][kk] = pk.v;
                    }
                }
            }
            if (ns_my > 0) {
                for (int Tc = tchalf * 8; Tc < tchalf * 8 + 8; ++Tc) {
                    float bias[4];
#pragma unroll
                    for (int t = 0; t < 4; ++t) bias[t] = blr2[(Tc * 4 + t) * 64 + lane];
                    f32x4 acc[2][4];
#pragma unroll
                    for (int si = 0; si < 2; ++si)
#pragma unroll
                        for (int t = 0; t < 4; ++t)
                            acc[si][t] = (f32x4){bias[t], bias[t], bias[t], bias[t]};
#pragma unroll
                    for (int kk = 0; kk < 8; ++kk) {
                        short8 Wf[4];
#pragma unroll
                        for (int t = 0; t < 4; ++t)
                            Wf[t] = *(const short8*)(W2k + ((size_t)((Tc * 4 + t) * 8 + kk) * 64 + lane) * 8);
#pragma unroll
                        for (int t = 0; t < 4; ++t) {
                            acc[0][t] = __builtin_amdgcn_mfma_f32_16x16x32_bf16(A2[0][kk], Wf[t], acc[0][t], 0, 0, 0);
                            if (ns_my > 1)
                                acc[1][t] = __builtin_amdgcn_mfma_f32_16x16x32_bf16(A2[1][kk], Wf[t], acc[1][t], 0, 0, 0);
                        }
                    }
#pragma unroll
                    for (int si = 0; si < 2; ++si) {
                        if (si < ns_my) {
                            const int zsl = sabs[si] % ring_steps;
                            float* zo_ = zf32 + ((size_t)zsl * 32 + m) * 16384 + (size_t)lane * 4;
#pragma unroll
                            for (int t = 0; t < 4; ++t)
                                *(f32x4*)(zo_ + (Tc * 4 + t) * 256) = acc[si][t];
                        }
                    }
                }
            }
            __syncthreads();
            if (tid == 0)
                __hip_atomic_store(&prod_flag[(w_ * 32 + m) * 4], 1u,
                                   __ATOMIC_RELEASE, __HIP_MEMORY_SCOPE_AGENT);
        }
    }
}

// ---------------------------------------------------------------------------
extern "C" void kernel_launch(void* const* d_in, const int* in_sizes, int n_in,
                              void* d_out, int out_size, void* d_ws, size_t ws_size,
                              hipStream_t stream)
{
    const float* motion = (const float*)d_in[0];
    const float* robot  = (const float*)d_in[1];
    const float* osr    = (const float*)d_in[2];
    const float* osi    = (const float*)d_in[3];
    const float* hist   = (const float*)d_in[4];
    const float* act    = (const float*)d_in[5];
    const float* ore    = (const float*)d_in[6];
    const float* oie    = (const float*)d_in[7];
    const float* Wm  = (const float*)d_in[8];  const float* bm  = (const float*)d_in[9];
    const float* Wr  = (const float*)d_in[10]; const float* br  = (const float*)d_in[11];
    const float* Wre = (const float*)d_in[12]; const float* bre = (const float*)d_in[13];
    const float* Wim = (const float*)d_in[14]; const float* bim = (const float*)d_in[15];
    const float* Wc  = (const float*)d_in[16]; const float* bc  = (const float*)d_in[17];
    const float* Wk  = (const float*)d_in[18];
    const float* Wrk = (const float*)d_in[19];
    const float* bl  = (const float*)d_in[20];
    const float* Wo  = (const float*)d_in[21]; const float* bo  = (const float*)d_in[22];

    char* ws = (char*)d_ws;
    float*          state     = (float*)(ws + 0);                  // 524288
    unsigned short* W2k       = (unsigned short*)(ws + 524288);    // 524288
    unsigned short* W2r       = (unsigned short*)(ws + 1048576);   // 524288
    float*          blr2      = (float*)(ws + 1572864);            // 16384
    unsigned int*   prod_flag = (unsigned int*)(ws + 1589248);     // 163840
    unsigned int*   cons_prog = (unsigned int*)(ws + 1753088);     // 2048
    float*          hfing     = (float*)(ws + 1755136);            // 524288 final-h scratch
    float*          zf32      = (float*)(ws + 2279424);            // f32 ring
    float*          out       = (float*)d_out;

    // adaptive ring: per-step z is 2 MB (32 tiles x 64 KB f32). UNCAPPED
    // (round-5 lesson: throttling producers costs 2.2x; locality cap bought
    // nothing -- z reads were already cache-served).
    size_t avail = (ws_size > 2279424) ? ws_size - 2279424 : 0;
    long rs_max = (long)(avail / 2097152);
    int WIN = 1, NW = 255, RS = 1;
    const int wins[4] = {8, 4, 2, 1};
    for (int i = 0; i < 4; ++i) {
        const int Wn = wins[i];
        const int nw = (NSTEP + Wn - 1) / Wn;
        long rs = rs_max / Wn; if (rs > nw) rs = nw;
        if (rs >= 2) { WIN = Wn; NW = nw; RS = (int)rs; break; }
        if (Wn == 1) { WIN = 1; NW = nw; RS = (int)(rs >= 1 ? rs : 1); }
    }
    int ring_steps = RS * WIN; if (ring_steps < 1) ring_steps = 1;
    const int WSH = (WIN == 8) ? 3 : (WIN == 4) ? 2 : (WIN == 2) ? 1 : 0;

    encoder_kernel<<<dim3(32), dim3(256), 0, stream>>>(
        motion, robot, osr, osi, ore, oie,
        Wm, bm, Wr, br, Wre, bre, Wim, bim, Wc, bc, state);
    prep_kernel<<<dim3(257), dim3(256), 0, stream>>>(
        Wk, Wrk, bl, W2k, W2r, blr2, prod_flag, cons_prog);
    fused_kernel<<<dim3(256), dim3(512), 0, stream>>>(
        hist, act, state, W2k, W2r, blr2, Wo, bo,
        zf32, hfing, prod_flag, cons_prog, out, WSH, NW, RS, ring_steps);
}

// Round 7
// 1751.262 us; speedup vs baseline: 2.4112x; 2.4112x over previous
//
#include <hip/hip_runtime.h>
#include <stdint.h>

// ---------------------------------------------------------------------------
// Critic: encoder -> 255-step LSTM (U=256, D_in=256) -> 1-unit relu head. B=512
//
// Round-10 design (root cause found: __launch_bounds__(512,2) promised 2
// co-resident units -> compiler budgeted 128 VGPRs/lane, but LDS=148KB caps
// at 1 block/CU anyway. Wres (192 regs) was spilled through scratch on the
// MFMA operand path since round 1 -- the ~6.4us/step floor).
//  - __launch_bounds__(512, 1): same real occupancy, 256-reg budget.
//  - z loads go DIRECTLY into MFMA accumulators in place (no zA/zB shadow
//    copies; saves 32 regs so Wres+acc+cc fits 256): accA(s+1) loaded right
//    after gates-half0 consumes accA(s); accB(s+1) after gates-half1.
//  - Depth-2 reverted (r6 regression). Ring uncapped (r5 lesson). lgkm-only
//    barrier, 6 reg + 2 LDS Wrk tiles/wave, window handshake: round-3 base.
// ---------------------------------------------------------------------------

#define NSTEP 255

typedef __attribute__((ext_vector_type(8))) short short8;   // 8 x bf16
typedef __attribute__((ext_vector_type(4))) float f32x4;

#define HSTR 280   // hbuf row stride in shorts (560 B, 16B-aligned)

__device__ __forceinline__ unsigned short f2bf(float f) {
    union { float f; unsigned int u; } v; v.f = f;
    unsigned int r = v.u + 0x7FFFu + ((v.u >> 16) & 1u);   // RNE
    return (unsigned short)(r >> 16);
}
__device__ __forceinline__ float fexp2(float x) { return __builtin_amdgcn_exp2f(x); }
__device__ __forceinline__ float frcp(float x)  { return __builtin_amdgcn_rcpf(x); }
__device__ __forceinline__ float sigm(float x)  { return frcp(1.0f + fexp2(-1.44269504f * x)); }
__device__ __forceinline__ float tanh_(float x) { return 1.0f - 2.0f * frcp(1.0f + fexp2(2.88539008f * x)); }

// ---------------------------------------------------------------------------
// Encoder: state = relu(concat(ms,rs,re,im) @ Wc + bc)   [512,256] fp32
// ---------------------------------------------------------------------------
__global__ __launch_bounds__(256)
void encoder_kernel(const float* __restrict__ motion, const float* __restrict__ robot,
                    const float* __restrict__ osr, const float* __restrict__ osi,
                    const float* __restrict__ ore, const float* __restrict__ oie,
                    const float* __restrict__ Wm, const float* __restrict__ bm,
                    const float* __restrict__ Wr, const float* __restrict__ br,
                    const float* __restrict__ Wre, const float* __restrict__ bre,
                    const float* __restrict__ Wim, const float* __restrict__ bim,
                    const float* __restrict__ Wc, const float* __restrict__ bc,
                    float* __restrict__ state)
{
    __shared__ float in_m[16][64];
    __shared__ float in_r[16][128];
    __shared__ float in_re[16][128];
    __shared__ float in_im[16][128];
    __shared__ float catb[16 * 768];
    const int t = threadIdx.x;
    const int m0 = blockIdx.x * 16;

    {
        int idx = t * 4; int row = idx >> 6, col = idx & 63;
        *(float4*)&in_m[row][col]       = *(const float4*)(motion + (m0 + row) * 64 + col);
        *(float4*)&in_re[row][col]      = *(const float4*)(osr + (m0 + row) * 64 + col);
        *(float4*)&in_re[row][64 + col] = *(const float4*)(ore + (m0 + row) * 64 + col);
        *(float4*)&in_im[row][col]      = *(const float4*)(osi + (m0 + row) * 64 + col);
        *(float4*)&in_im[row][64 + col] = *(const float4*)(oie + (m0 + row) * 64 + col);
    }
    for (int p = 0; p < 2; ++p) {
        int idx = (t + p * 256) * 4; int row = idx >> 7, col = idx & 127;
        *(float4*)&in_r[row][col] = *(const float4*)(robot + (m0 + row) * 128 + col);
    }
    __syncthreads();

    for (int row = 0; row < 16; ++row) {
        {
            float s = bm[t];
            for (int k = 0; k < 64; ++k) s += in_m[row][k] * Wm[k * 256 + t];
            catb[row * 768 + t] = fmaxf(s, 0.0f);
        }
        {
            float s = br[t];
            for (int k = 0; k < 128; ++k) s += in_r[row][k] * Wr[k * 256 + t];
            catb[row * 768 + 256 + t] = fmaxf(s, 0.0f);
        }
        if (t < 128) {
            float s = bre[t];
            for (int k = 0; k < 128; ++k) s += in_re[row][k] * Wre[k * 128 + t];
            catb[row * 768 + 512 + t] = fmaxf(s, 0.0f);
        } else {
            const int u = t - 128;
            float s = bim[u];
            for (int k = 0; k < 128; ++k) s += in_im[row][k] * Wim[k * 128 + u];
            catb[row * 768 + 640 + u] = fmaxf(s, 0.0f);
        }
    }
    __syncthreads();

    for (int r0 = 0; r0 < 16; r0 += 4) {
        float a0 = bc[t], a1 = bc[t], a2 = bc[t], a3 = bc[t];
        for (int j = 0; j < 768; ++j) {
            const float wv = Wc[j * 256 + t];
            a0 += catb[(r0 + 0) * 768 + j] * wv;
            a1 += catb[(r0 + 1) * 768 + j] * wv;
            a2 += catb[(r0 + 2) * 768 + j] * wv;
            a3 += catb[(r0 + 3) * 768 + j] * wv;
        }
        state[(m0 + r0 + 0) * 256 + t] = fmaxf(a0, 0.0f);
        state[(m0 + r0 + 1) * 256 + t] = fmaxf(a1, 0.0f);
        state[(m0 + r0 + 2) * 256 + t] = fmaxf(a2, 0.0f);
        state[(m0 + r0 + 3) * 256 + t] = fmaxf(a3, 0.0f);
    }
}

// ---------------------------------------------------------------------------
// Prep: W2k/W2r in frag-linear layout [(T*8+kk)*64+lane][8], bf16.
// ---------------------------------------------------------------------------
__global__ __launch_bounds__(256)
void prep_kernel(const float* __restrict__ Wk, const float* __restrict__ Wrk,
                 const float* __restrict__ bl,
                 unsigned short* __restrict__ W2k, unsigned short* __restrict__ W2r,
                 float* __restrict__ blr2,
                 unsigned int* __restrict__ prod_flag, unsigned int* __restrict__ cons_prog)
{
    const int blk = blockIdx.x, t = threadIdx.x;
    if (blk < 256) {
        const int mat = blk >> 7;
        const int idx = (blk & 127) * 256 + t;      // (T*8+kk)*64+lane
        const int T = idx >> 9, kk = (idx >> 6) & 7, lane = idx & 63;
        const int q = lane >> 4, cid = lane & 15;
        const int wv = T >> 4, gam = (T >> 2) & 3, g = T & 3;
        const int col = g * 256 + wv * 64 + gam * 16 + cid;
        const float* W = mat ? Wrk : Wk;
        unsigned short* O = mat ? W2r : W2k;
#pragma unroll
        for (int j = 0; j < 8; ++j) {
            const int k = kk * 32 + q * 8 + j;
            O[(size_t)idx * 8 + j] = f2bf(W[(size_t)k * 1024 + col]);
        }
    } else {
        for (int e = t; e < 4096; e += 256) {
            const int T = e >> 6, lane = e & 63, cid = lane & 15;
            const int wv = T >> 4, gam = (T >> 2) & 3, g = T & 3;
            blr2[e] = bl[g * 256 + wv * 64 + gam * 16 + cid];
        }
        for (int i = t; i < 40960; i += 256) prod_flag[i] = 0u;
        for (int i = t; i < 512; i += 256) cons_prog[i] = 0u;
    }
}

// ---------------------------------------------------------------------------
// Fused: blocks 0..31 = consumers (recurrence, 8 waves), 32..255 = producers.
// z ring is f32 C-fragments: z[(slot*32+m)*16384 + (T*64+lane)*4 .. +3]
// ---------------------------------------------------------------------------
__global__ __launch_bounds__(512, 1)
void fused_kernel(const float* __restrict__ hist, const float* __restrict__ act,
                  const float* __restrict__ state,
                  const unsigned short* __restrict__ W2k, const unsigned short* __restrict__ W2r,
                  const float* __restrict__ blr2,
                  const float* __restrict__ Wo, const float* __restrict__ bo_p,
                  float* __restrict__ zf32, float* __restrict__ hfing,
                  unsigned int* __restrict__ prod_flag, unsigned int* __restrict__ cons_prog,
                  float* __restrict__ out,
                  int WSH, int NW, int RS, int ring_steps)
{
    __shared__ __align__(16) unsigned char smem[148992];
    unsigned short* ldsW = (unsigned short*)smem;                 // 131072 B (2 Wrk tiles / wave)
    unsigned short* hbuf0 = (unsigned short*)(smem + 131072);     // 16*HSTR*2 = 8960 B
    unsigned short* hbuf1 = (unsigned short*)(smem + 140032);     // 8960 B

    const int tid = threadIdx.x;
    const int w = tid >> 6, lane = tid & 63, q = lane >> 4, cid = lane & 15;
    const int bx = blockIdx.x;
    const int WIN = 1 << WSH, WMASK = WIN - 1;

    if (bx < 32) {
        // ======================= CONSUMER =======================
        const int m = bx, m0 = m * 16;
        const int u0 = (w >> 1) * 64 + ((w & 1) * 2 + 0) * 16 + cid;
        const int u1 = u0 + 16;

        // register-resident Wrk: tiles j=0..5 (192 regs -- now actually fits)
        short8 Wres[6][8];
#pragma unroll
        for (int t = 0; t < 6; ++t) {
#pragma unroll
            for (int kk = 0; kk < 8; ++kk)
                Wres[t][kk] = *(const short8*)(W2r + ((size_t)((w * 8 + t) * 8 + kk) * 64 + lane) * 8);
        }
        // LDS-resident Wrk: tiles j=6,7
#pragma unroll
        for (int tt = 0; tt < 2; ++tt) {
#pragma unroll
            for (int kk = 0; kk < 8; ++kk) {
                short8 f = *(const short8*)(W2r + ((size_t)((w * 8 + 6 + tt) * 8 + kk) * 64 + lane) * 8);
                *(short8*)(ldsW + (((w * 2 + tt) * 8 + kk) * 64 + lane) * 8) = f;
            }
        }
        // h^0 = bf16(state tile)
        {
            const int row = tid >> 5, c0 = (tid & 31) * 8;
            const float* sp = state + (size_t)(m0 + row) * 256 + c0;
            const float4 a = *(const float4*)sp;
            const float4 b = *(const float4*)(sp + 4);
            union { unsigned short us[8]; short8 v; } pk;
            pk.us[0] = f2bf(a.x); pk.us[1] = f2bf(a.y); pk.us[2] = f2bf(a.z); pk.us[3] = f2bf(a.w);
            pk.us[4] = f2bf(b.x); pk.us[5] = f2bf(b.y); pk.us[6] = f2bf(b.z); pk.us[7] = f2bf(b.w);
            *(short8*)(hbuf0 + row * HSTR + c0) = pk.v;
        }
        // c^0
        float cc[8];
#pragma unroll
        for (int h = 0; h < 2; ++h)
#pragma unroll
            for (int r = 0; r < 4; ++r)
                cc[h * 4 + r] = state[(size_t)(m0 + q * 4 + r) * 256 + (h ? u1 : u0)];

        __syncthreads();

        unsigned short* hcur = hbuf0;
        unsigned short* hnxt = hbuf1;
        int zslot = 0;
        // z lives IN the accumulators (in-place C-in): 32 regs total.
        f32x4 accA[4], accB[4];
        const float* zbw = zf32 + (size_t)lane * 4 + (size_t)w * 2048;

        // prologue: window 0 acquire + z(s=0) both halves straight into acc
        while (__hip_atomic_load(&prod_flag[m * 4],
                                 __ATOMIC_ACQUIRE, __HIP_MEMORY_SCOPE_AGENT) == 0)
            __builtin_amdgcn_s_sleep(1);
        {
            const float* zb = zbw + (size_t)m * 16384;
#pragma unroll
            for (int g = 0; g < 4; ++g) {
                accA[g] = *(const f32x4*)(zb + g * 256);
                accB[g] = *(const f32x4*)(zb + 1024 + g * 256);
            }
        }

        for (int s = 0; s < NSTEP; ++s) {
            const bool last = (s == NSTEP - 1);

            // legacy path (RS<2): synchronous load every step
            if (RS < 2 && s > 0) {
                if ((s & WMASK) == 0) {
                    const int f = s >> WSH;
                    while (__hip_atomic_load(&prod_flag[(f * 32 + m) * 4],
                                             __ATOMIC_ACQUIRE, __HIP_MEMORY_SCOPE_AGENT) == 0)
                        __builtin_amdgcn_s_sleep(1);
                }
                const float* zb = zbw + ((size_t)zslot * 32 + m) * 16384;
#pragma unroll
                for (int g = 0; g < 4; ++g) {
                    accA[g] = *(const f32x4*)(zb + g * 256);
                    accB[g] = *(const f32x4*)(zb + 1024 + g * 256);
                }
            }

            const unsigned short* hrow = hcur + cid * HSTR + q * 8;
            const int znext = (zslot + 1 == ring_steps) ? 0 : zslot + 1;

            // half 0: tiles 0..3 register-resident; C-in = accA (z preloaded)
            __builtin_amdgcn_s_setprio(1);
#pragma unroll
            for (int kk = 0; kk < 8; ++kk) {
                const short8 a = *(const short8*)(hrow + kk * 32);
                accA[0] = __builtin_amdgcn_mfma_f32_16x16x32_bf16(a, Wres[0][kk], accA[0], 0, 0, 0);
                accA[1] = __builtin_amdgcn_mfma_f32_16x16x32_bf16(a, Wres[1][kk], accA[1], 0, 0, 0);
                accA[2] = __builtin_amdgcn_mfma_f32_16x16x32_bf16(a, Wres[2][kk], accA[2], 0, 0, 0);
                accA[3] = __builtin_amdgcn_mfma_f32_16x16x32_bf16(a, Wres[3][kk], accA[3], 0, 0, 0);
            }
            __builtin_amdgcn_s_setprio(0);

            // gates half 0 (consume accA)
#pragma unroll
            for (int r = 0; r < 4; ++r) {
                const float c = sigm(accA[1][r]) * cc[r] + sigm(accA[0][r]) * tanh_(accA[2][r]);
                cc[r] = c;
                const float hv = sigm(accA[3][r]) * tanh_(c);
                if (!last) hnxt[(q * 4 + r) * HSTR + u0] = f2bf(hv);
                else       hfing[(size_t)(m0 + q * 4 + r) * 256 + u0] = hv;
            }

            // accA is dead: reload it with z(s+1) half-0 (cover = half1+barrier
            // + next half0 chain). At a window boundary acquire the flag first.
            if (!last && RS >= 2) {
                if (((s + 1) & WMASK) == 0) {
                    const int fn = (s + 1) >> WSH;
                    while (__hip_atomic_load(&prod_flag[(fn * 32 + m) * 4],
                                             __ATOMIC_ACQUIRE, __HIP_MEMORY_SCOPE_AGENT) == 0)
                        __builtin_amdgcn_s_sleep(1);
                }
                const float* zbn = zbw + ((size_t)znext * 32 + m) * 16384;
#pragma unroll
                for (int g = 0; g < 4; ++g)
                    accA[g] = *(const f32x4*)(zbn + g * 256);
            }

            // half 1: tiles 4,5 resident + 6,7 LDS; C-in = accB
            __builtin_amdgcn_s_setprio(1);
#pragma unroll
            for (int kk = 0; kk < 8; ++kk) {
                const short8 a = *(const short8*)(hrow + kk * 32);
                accB[0] = __builtin_amdgcn_mfma_f32_16x16x32_bf16(a, Wres[4][kk], accB[0], 0, 0, 0);
                accB[1] = __builtin_amdgcn_mfma_f32_16x16x32_bf16(a, Wres[5][kk], accB[1], 0, 0, 0);
                const short8 b6 = *(const short8*)(ldsW + (((w * 2 + 0) * 8 + kk) * 64 + lane) * 8);
                accB[2] = __builtin_amdgcn_mfma_f32_16x16x32_bf16(a, b6, accB[2], 0, 0, 0);
                const short8 b7 = *(const short8*)(ldsW + (((w * 2 + 1) * 8 + kk) * 64 + lane) * 8);
                accB[3] = __builtin_amdgcn_mfma_f32_16x16x32_bf16(a, b7, accB[3], 0, 0, 0);
            }
            __builtin_amdgcn_s_setprio(0);

            // gates half 1 (consume accB)
#pragma unroll
            for (int r = 0; r < 4; ++r) {
                const float c = sigm(accB[1][r]) * cc[4 + r] + sigm(accB[0][r]) * tanh_(accB[2][r]);
                cc[4 + r] = c;
                const float hv = sigm(accB[3][r]) * tanh_(c);
                if (!last) hnxt[(q * 4 + r) * HSTR + u1] = f2bf(hv);
                else       hfing[(size_t)(m0 + q * 4 + r) * 256 + u1] = hv;
            }

            // accB is dead: reload with z(s+1) half-1 (cover = barrier +
            // next step's half0 MFMA chain). Same slot/flag as accA reload.
            if (!last && RS >= 2) {
                const float* zbn = zbw + ((size_t)znext * 32 + m) * 16384;
#pragma unroll
                for (int g = 0; g < 4; ++g)
                    accB[g] = *(const f32x4*)(zbn + 1024 + g * 256);
            }

            // lgkm-only barrier: h-exchange needs LDS visibility ONLY.
            asm volatile("s_waitcnt lgkmcnt(0)" ::: "memory");
            __builtin_amdgcn_s_barrier();

            { unsigned short* t_ = hcur; hcur = hnxt; hnxt = t_; }
            if (((s + 1) & WMASK) == 0 && tid == 0)
                __hip_atomic_store(&cons_prog[m * 16], (unsigned)((s + 1) >> WSH),
                                   __ATOMIC_RELEASE, __HIP_MEMORY_SCOPE_AGENT);
            zslot = znext;
        }

        __syncthreads();   // full drain before head

        // head: out = relu(h_final @ Wo + bo)
        float* redL = (float*)smem;
        if (tid < 256) {
            const int row = tid >> 4, c16 = tid & 15;
            float part = 0.0f;
#pragma unroll
            for (int j = 0; j < 16; ++j) {
                const int u = c16 + j * 16;
                part += hfing[(size_t)(m0 + row) * 256 + u] * Wo[u];
            }
            redL[row * 16 + c16] = part;
        }
        __syncthreads();
        if (tid < 16) {
            float sum = 0.0f;
#pragma unroll
            for (int j = 0; j < 16; ++j) sum += redL[tid * 16 + j];
            out[m0 + tid] = fmaxf(sum + bo_p[0], 0.0f);
        }
    } else {
        // ======================= PRODUCER =======================
        const int p = bx - 32;
        const int total = NW * 32;
        const int slot0 = w & 3, tchalf = w >> 2;   // 4 step-slots x 2 Tc halves
        for (int tau = p; tau < total; tau += 224) {
            const int w_ = tau >> 5, m = tau & 31, m0 = m * 16;
            const int nst = (WIN < NSTEP - w_ * WIN) ? WIN : (NSTEP - w_ * WIN);
            if (w_ >= RS) {
                const unsigned need = (unsigned)(w_ - RS + 1);
                while (__hip_atomic_load(&cons_prog[m * 16],
                                         __ATOMIC_ACQUIRE, __HIP_MEMORY_SCOPE_AGENT) < need)
                    __builtin_amdgcn_s_sleep(4);
            }
            int ns_my = 0; int sabs[2] = {0, 0};
            for (int sl = slot0; sl < nst; sl += 4) { if (ns_my < 2) sabs[ns_my++] = w_ * WIN + sl; }

            short8 A2[2][8];
#pragma unroll
            for (int si = 0; si < 2; ++si) {
                if (si < ns_my) {
                    const int s = sabs[si];
                    const float* xs = (s < 127)
                        ? hist + ((size_t)(m0 + cid) * 128 + s) * 256
                        : act + ((size_t)(m0 + cid) * 128 + (s - 127)) * 256;
#pragma unroll
                    for (int kk = 0; kk < 8; ++kk) {
                        const float4 a = *(const float4*)(xs + kk * 32 + q * 8);
                        const float4 b = *(const float4*)(xs + kk * 32 + q * 8 + 4);
                        union { unsigned short us[8]; short8 v; } pk;
                        pk.us[0] = f2bf(a.x); pk.us[1] = f2bf(a.y);
                        pk.us[2] = f2bf(a.z); pk.us[3] = f2bf(a.w);
                        pk.us[4] = f2bf(b.x); pk.us[5] = f2bf(b.y);
                        pk.us[6] = f2bf(b.z); pk.us[7] = f2bf(b.w);
                        A2[si][kk] = pk.v;
                    }
                }
            }
            if (ns_my > 0) {
                for (int Tc = tchalf * 8; Tc < tchalf * 8 + 8; ++Tc) {
                    float bias[4];
#pragma unroll
                    for (int t = 0; t < 4; ++t) bias[t] = blr2[(Tc * 4 + t) * 64 + lane];
                    f32x4 acc[2][4];
#pragma unroll
                    for (int si = 0; si < 2; ++si)
#pragma unroll
                        for (int t = 0; t < 4; ++t)
                            acc[si][t] = (f32x4){bias[t], bias[t], bias[t], bias[t]};
#pragma unroll
                    for (int kk = 0; kk < 8; ++kk) {
                        short8 Wf[4];
#pragma unroll
                        for (int t = 0; t < 4; ++t)
                            Wf[t] = *(const short8*)(W2k + ((size_t)((Tc * 4 + t) * 8 + kk) * 64 + lane) * 8);
#pragma unroll
                        for (int t = 0; t < 4; ++t) {
                            acc[0][t] = __builtin_amdgcn_mfma_f32_16x16x32_bf16(A2[0][kk], Wf[t], acc[0][t], 0, 0, 0);
                            if (ns_my > 1)
                                acc[1][t] = __builtin_amdgcn_mfma_f32_16x16x32_bf16(A2[1][kk], Wf[t], acc[1][t], 0, 0, 0);
                        }
                    }
#pragma unroll
                    for (int si = 0; si < 2; ++si) {
                        if (si < ns_my) {
                            const int zsl = sabs[si] % ring_steps;
                            float* zo_ = zf32 + ((size_t)zsl * 32 + m) * 16384 + (size_t)lane * 4;
#pragma unroll
                            for (int t = 0; t < 4; ++t)
                                *(f32x4*)(zo_ + (Tc * 4 + t) * 256) = acc[si][t];
                        }
                    }
                }
            }
            __syncthreads();
            if (tid == 0)
                __hip_atomic_store(&prod_flag[(w_ * 32 + m) * 4], 1u,
                                   __ATOMIC_RELEASE, __HIP_MEMORY_SCOPE_AGENT);
        }
    }
}

// ---------------------------------------------------------------------------
extern "C" void kernel_launch(void* const* d_in, const int* in_sizes, int n_in,
                              void* d_out, int out_size, void* d_ws, size_t ws_size,
                              hipStream_t stream)
{
    const float* motion = (const float*)d_in[0];
    const float* robot  = (const float*)d_in[1];
    const float* osr    = (const float*)d_in[2];
    const float* osi    = (const float*)d_in[3];
    const float* hist   = (const float*)d_in[4];
    const float* act    = (const float*)d_in[5];
    const float* ore    = (const float*)d_in[6];
    const float* oie    = (const float*)d_in[7];
    const float* Wm  = (const float*)d_in[8];  const float* bm  = (const float*)d_in[9];
    const float* Wr  = (const float*)d_in[10]; const float* br  = (const float*)d_in[11];
    const float* Wre = (const float*)d_in[12]; const float* bre = (const float*)d_in[13];
    const float* Wim = (const float*)d_in[14]; const float* bim = (const float*)d_in[15];
    const float* Wc  = (const float*)d_in[16]; const float* bc  = (const float*)d_in[17];
    const float* Wk  = (const float*)d_in[18];
    const float* Wrk = (const float*)d_in[19];
    const float* bl  = (const float*)d_in[20];
    const float* Wo  = (const float*)d_in[21]; const float* bo  = (const float*)d_in[22];

    char* ws = (char*)d_ws;
    float*          state     = (float*)(ws + 0);                  // 524288
    unsigned short* W2k       = (unsigned short*)(ws + 524288);    // 524288
    unsigned short* W2r       = (unsigned short*)(ws + 1048576);   // 524288
    float*          blr2      = (float*)(ws + 1572864);            // 16384
    unsigned int*   prod_flag = (unsigned int*)(ws + 1589248);     // 163840
    unsigned int*   cons_prog = (unsigned int*)(ws + 1753088);     // 2048
    float*          hfing     = (float*)(ws + 1755136);            // 524288 final-h scratch
    float*          zf32      = (float*)(ws + 2279424);            // f32 ring
    float*          out       = (float*)d_out;

    // adaptive ring: per-step z is 2 MB (32 tiles x 64 KB f32). UNCAPPED.
    size_t avail = (ws_size > 2279424) ? ws_size - 2279424 : 0;
    long rs_max = (long)(avail / 2097152);
    int WIN = 1, NW = 255, RS = 1;
    const int wins[4] = {8, 4, 2, 1};
    for (int i = 0; i < 4; ++i) {
        const int Wn = wins[i];
        const int nw = (NSTEP + Wn - 1) / Wn;
        long rs = rs_max / Wn; if (rs > nw) rs = nw;
        if (rs >= 2) { WIN = Wn; NW = nw; RS = (int)rs; break; }
        if (Wn == 1) { WIN = 1; NW = nw; RS = (int)(rs >= 1 ? rs : 1); }
    }
    int ring_steps = RS * WIN; if (ring_steps < 1) ring_steps = 1;
    const int WSH = (WIN == 8) ? 3 : (WIN == 4) ? 2 : (WIN == 2) ? 1 : 0;

    encoder_kernel<<<dim3(32), dim3(256), 0, stream>>>(
        motion, robot, osr, osi, ore, oie,
        Wm, bm, Wr, br, Wre, bre, Wim, bim, Wc, bc, state);
    prep_kernel<<<dim3(257), dim3(256), 0, stream>>>(
        Wk, Wrk, bl, W2k, W2r, blr2, prod_flag, cons_prog);
    fused_kernel<<<dim3(256), dim3(512), 0, stream>>>(
        hist, act, state, W2k, W2r, blr2, Wo, bo,
        zf32, hfing, prod_flag, cons_prog, out, WSH, NW, RS, ring_steps);
}

// Round 8
// 1747.915 us; speedup vs baseline: 2.4158x; 1.0019x over previous
//
#include <hip/hip_runtime.h>
#include <stdint.h>

// ---------------------------------------------------------------------------
// Critic: encoder -> 255-step LSTM (U=256, D_in=256) -> 1-unit relu head. B=512
//
// Round-11 design: SPLIT the producer/consumer fused kernel into two clean
// phases to remove (and measure) handshake/interference cost:
//  - zgemm_kernel: all z = x@Wk + bl, 512 blocks, no flags/gating. Writes the
//    full 255-step f32 ring (needs 534 MB workspace; r5-vs-r7 behavior implies
//    the ws holds it -- guarded fallback to the r7 fused kernel otherwise).
//  - recur_kernel: 32 blocks, recurrence ONLY. Zero atomics/acquires/spins
//    (kernel-boundary visibility). z slot = step index, in-place acc reload
//    (verified r7 pattern), lgkm-only barrier, 6 reg + 2 LDS Wrk tiles/wave,
//    __launch_bounds__(512,1) so Wres lives in unified VGPR/AGPR file.
//  - rocprof now reports the pure recurrence floor as its own dispatch.
// ---------------------------------------------------------------------------

#define NSTEP 255

typedef __attribute__((ext_vector_type(8))) short short8;   // 8 x bf16
typedef __attribute__((ext_vector_type(4))) float f32x4;

#define HSTR 280   // hbuf row stride in shorts (560 B, 16B-aligned)

__device__ __forceinline__ unsigned short f2bf(float f) {
    union { float f; unsigned int u; } v; v.f = f;
    unsigned int r = v.u + 0x7FFFu + ((v.u >> 16) & 1u);   // RNE
    return (unsigned short)(r >> 16);
}
__device__ __forceinline__ float fexp2(float x) { return __builtin_amdgcn_exp2f(x); }
__device__ __forceinline__ float frcp(float x)  { return __builtin_amdgcn_rcpf(x); }
__device__ __forceinline__ float sigm(float x)  { return frcp(1.0f + fexp2(-1.44269504f * x)); }
__device__ __forceinline__ float tanh_(float x) { return 1.0f - 2.0f * frcp(1.0f + fexp2(2.88539008f * x)); }

// ---------------------------------------------------------------------------
// Encoder: state = relu(concat(ms,rs,re,im) @ Wc + bc)   [512,256] fp32
// ---------------------------------------------------------------------------
__global__ __launch_bounds__(256)
void encoder_kernel(const float* __restrict__ motion, const float* __restrict__ robot,
                    const float* __restrict__ osr, const float* __restrict__ osi,
                    const float* __restrict__ ore, const float* __restrict__ oie,
                    const float* __restrict__ Wm, const float* __restrict__ bm,
                    const float* __restrict__ Wr, const float* __restrict__ br,
                    const float* __restrict__ Wre, const float* __restrict__ bre,
                    const float* __restrict__ Wim, const float* __restrict__ bim,
                    const float* __restrict__ Wc, const float* __restrict__ bc,
                    float* __restrict__ state)
{
    __shared__ float in_m[16][64];
    __shared__ float in_r[16][128];
    __shared__ float in_re[16][128];
    __shared__ float in_im[16][128];
    __shared__ float catb[16 * 768];
    const int t = threadIdx.x;
    const int m0 = blockIdx.x * 16;

    {
        int idx = t * 4; int row = idx >> 6, col = idx & 63;
        *(float4*)&in_m[row][col]       = *(const float4*)(motion + (m0 + row) * 64 + col);
        *(float4*)&in_re[row][col]      = *(const float4*)(osr + (m0 + row) * 64 + col);
        *(float4*)&in_re[row][64 + col] = *(const float4*)(ore + (m0 + row) * 64 + col);
        *(float4*)&in_im[row][col]      = *(const float4*)(osi + (m0 + row) * 64 + col);
        *(float4*)&in_im[row][64 + col] = *(const float4*)(oie + (m0 + row) * 64 + col);
    }
    for (int p = 0; p < 2; ++p) {
        int idx = (t + p * 256) * 4; int row = idx >> 7, col = idx & 127;
        *(float4*)&in_r[row][col] = *(const float4*)(robot + (m0 + row) * 128 + col);
    }
    __syncthreads();

    for (int row = 0; row < 16; ++row) {
        {
            float s = bm[t];
            for (int k = 0; k < 64; ++k) s += in_m[row][k] * Wm[k * 256 + t];
            catb[row * 768 + t] = fmaxf(s, 0.0f);
        }
        {
            float s = br[t];
            for (int k = 0; k < 128; ++k) s += in_r[row][k] * Wr[k * 256 + t];
            catb[row * 768 + 256 + t] = fmaxf(s, 0.0f);
        }
        if (t < 128) {
            float s = bre[t];
            for (int k = 0; k < 128; ++k) s += in_re[row][k] * Wre[k * 128 + t];
            catb[row * 768 + 512 + t] = fmaxf(s, 0.0f);
        } else {
            const int u = t - 128;
            float s = bim[u];
            for (int k = 0; k < 128; ++k) s += in_im[row][k] * Wim[k * 128 + u];
            catb[row * 768 + 640 + u] = fmaxf(s, 0.0f);
        }
    }
    __syncthreads();

    for (int r0 = 0; r0 < 16; r0 += 4) {
        float a0 = bc[t], a1 = bc[t], a2 = bc[t], a3 = bc[t];
        for (int j = 0; j < 768; ++j) {
            const float wv = Wc[j * 256 + t];
            a0 += catb[(r0 + 0) * 768 + j] * wv;
            a1 += catb[(r0 + 1) * 768 + j] * wv;
            a2 += catb[(r0 + 2) * 768 + j] * wv;
            a3 += catb[(r0 + 3) * 768 + j] * wv;
        }
        state[(m0 + r0 + 0) * 256 + t] = fmaxf(a0, 0.0f);
        state[(m0 + r0 + 1) * 256 + t] = fmaxf(a1, 0.0f);
        state[(m0 + r0 + 2) * 256 + t] = fmaxf(a2, 0.0f);
        state[(m0 + r0 + 3) * 256 + t] = fmaxf(a3, 0.0f);
    }
}

// ---------------------------------------------------------------------------
// Prep: W2k/W2r in frag-linear layout [(T*8+kk)*64+lane][8], bf16.
// ---------------------------------------------------------------------------
__global__ __launch_bounds__(256)
void prep_kernel(const float* __restrict__ Wk, const float* __restrict__ Wrk,
                 const float* __restrict__ bl,
                 unsigned short* __restrict__ W2k, unsigned short* __restrict__ W2r,
                 float* __restrict__ blr2,
                 unsigned int* __restrict__ prod_flag, unsigned int* __restrict__ cons_prog)
{
    const int blk = blockIdx.x, t = threadIdx.x;
    if (blk < 256) {
        const int mat = blk >> 7;
        const int idx = (blk & 127) * 256 + t;      // (T*8+kk)*64+lane
        const int T = idx >> 9, kk = (idx >> 6) & 7, lane = idx & 63;
        const int q = lane >> 4, cid = lane & 15;
        const int wv = T >> 4, gam = (T >> 2) & 3, g = T & 3;
        const int col = g * 256 + wv * 64 + gam * 16 + cid;
        const float* W = mat ? Wrk : Wk;
        unsigned short* O = mat ? W2r : W2k;
#pragma unroll
        for (int j = 0; j < 8; ++j) {
            const int k = kk * 32 + q * 8 + j;
            O[(size_t)idx * 8 + j] = f2bf(W[(size_t)k * 1024 + col]);
        }
    } else {
        for (int e = t; e < 4096; e += 256) {
            const int T = e >> 6, lane = e & 63, cid = lane & 15;
            const int wv = T >> 4, gam = (T >> 2) & 3, g = T & 3;
            blr2[e] = bl[g * 256 + wv * 64 + gam * 16 + cid];
        }
        for (int i = t; i < 40960; i += 256) prod_flag[i] = 0u;
        for (int i = t; i < 512; i += 256) cons_prog[i] = 0u;
    }
}

// ---------------------------------------------------------------------------
// Phase A: z[s] = x_s @ Wk + bl for ALL steps. 512 blocks, no gating/flags.
// Task tau = (window w_ in 0..31) * 32 + tile m; 8 waves = 4 slots x 2 halves.
// ---------------------------------------------------------------------------
__global__ __launch_bounds__(512, 2)
void zgemm_kernel(const float* __restrict__ hist, const float* __restrict__ act,
                  const unsigned short* __restrict__ W2k, const float* __restrict__ blr2,
                  float* __restrict__ zf32)
{
    const int tid = threadIdx.x;
    const int w = tid >> 6, lane = tid & 63, q = lane >> 4, cid = lane & 15;
    const int slot0 = w & 3, tchalf = w >> 2;
    const int total = 32 * 32;   // 32 windows (WIN=8) x 32 tiles

    for (int tau = blockIdx.x; tau < total; tau += 512) {
        const int w_ = tau >> 5, m = tau & 31, m0 = m * 16;
        const int nst = (8 < NSTEP - w_ * 8) ? 8 : (NSTEP - w_ * 8);
        int ns_my = 0; int sabs[2] = {0, 0};
        for (int sl = slot0; sl < nst; sl += 4) { if (ns_my < 2) sabs[ns_my++] = w_ * 8 + sl; }
        if (ns_my == 0) continue;

        short8 A2[2][8];
#pragma unroll
        for (int si = 0; si < 2; ++si) {
            if (si < ns_my) {
                const int s = sabs[si];
                const float* xs = (s < 127)
                    ? hist + ((size_t)(m0 + cid) * 128 + s) * 256
                    : act + ((size_t)(m0 + cid) * 128 + (s - 127)) * 256;
#pragma unroll
                for (int kk = 0; kk < 8; ++kk) {
                    const float4 a = *(const float4*)(xs + kk * 32 + q * 8);
                    const float4 b = *(const float4*)(xs + kk * 32 + q * 8 + 4);
                    union { unsigned short us[8]; short8 v; } pk;
                    pk.us[0] = f2bf(a.x); pk.us[1] = f2bf(a.y);
                    pk.us[2] = f2bf(a.z); pk.us[3] = f2bf(a.w);
                    pk.us[4] = f2bf(b.x); pk.us[5] = f2bf(b.y);
                    pk.us[6] = f2bf(b.z); pk.us[7] = f2bf(b.w);
                    A2[si][kk] = pk.v;
                }
            }
        }
        for (int Tc = tchalf * 8; Tc < tchalf * 8 + 8; ++Tc) {
            float bias[4];
#pragma unroll
            for (int t = 0; t < 4; ++t) bias[t] = blr2[(Tc * 4 + t) * 64 + lane];
            f32x4 acc[2][4];
#pragma unroll
            for (int si = 0; si < 2; ++si)
#pragma unroll
                for (int t = 0; t < 4; ++t)
                    acc[si][t] = (f32x4){bias[t], bias[t], bias[t], bias[t]};
#pragma unroll
            for (int kk = 0; kk < 8; ++kk) {
                short8 Wf[4];
#pragma unroll
                for (int t = 0; t < 4; ++t)
                    Wf[t] = *(const short8*)(W2k + ((size_t)((Tc * 4 + t) * 8 + kk) * 64 + lane) * 8);
#pragma unroll
                for (int t = 0; t < 4; ++t) {
                    acc[0][t] = __builtin_amdgcn_mfma_f32_16x16x32_bf16(A2[0][kk], Wf[t], acc[0][t], 0, 0, 0);
                    if (ns_my > 1)
                        acc[1][t] = __builtin_amdgcn_mfma_f32_16x16x32_bf16(A2[1][kk], Wf[t], acc[1][t], 0, 0, 0);
                }
            }
#pragma unroll
            for (int si = 0; si < 2; ++si) {
                if (si < ns_my) {
                    float* zo_ = zf32 + ((size_t)sabs[si] * 32 + m) * 16384 + (size_t)lane * 4;
#pragma unroll
                    for (int t = 0; t < 4; ++t)
                        *(f32x4*)(zo_ + (Tc * 4 + t) * 256) = acc[si][t];
                }
            }
        }
    }
}

// ---------------------------------------------------------------------------
// Phase B: recurrence ONLY. 32 blocks x 8 waves. No atomics, no spins.
// z slot = step index (full 255-slot ring). In-place acc reload (r7 pattern).
// ---------------------------------------------------------------------------
__global__ __launch_bounds__(512, 1)
void recur_kernel(const float* __restrict__ state,
                  const unsigned short* __restrict__ W2r,
                  const float* __restrict__ Wo, const float* __restrict__ bo_p,
                  const float* __restrict__ zf32, float* __restrict__ hfing,
                  float* __restrict__ out)
{
    __shared__ __align__(16) unsigned char smem[148992];
    unsigned short* ldsW = (unsigned short*)smem;                 // 131072 B
    unsigned short* hbuf0 = (unsigned short*)(smem + 131072);     // 8960 B
    unsigned short* hbuf1 = (unsigned short*)(smem + 140032);     // 8960 B

    const int tid = threadIdx.x;
    const int w = tid >> 6, lane = tid & 63, q = lane >> 4, cid = lane & 15;
    const int m = blockIdx.x, m0 = m * 16;
    const int u0 = (w >> 1) * 64 + ((w & 1) * 2 + 0) * 16 + cid;
    const int u1 = u0 + 16;

    // register/AGPR-resident Wrk: tiles j=0..5
    short8 Wres[6][8];
#pragma unroll
    for (int t = 0; t < 6; ++t) {
#pragma unroll
        for (int kk = 0; kk < 8; ++kk)
            Wres[t][kk] = *(const short8*)(W2r + ((size_t)((w * 8 + t) * 8 + kk) * 64 + lane) * 8);
    }
    // LDS-resident Wrk: tiles j=6,7
#pragma unroll
    for (int tt = 0; tt < 2; ++tt) {
#pragma unroll
        for (int kk = 0; kk < 8; ++kk) {
            short8 f = *(const short8*)(W2r + ((size_t)((w * 8 + 6 + tt) * 8 + kk) * 64 + lane) * 8);
            *(short8*)(ldsW + (((w * 2 + tt) * 8 + kk) * 64 + lane) * 8) = f;
        }
    }
    // h^0 = bf16(state tile)
    {
        const int row = tid >> 5, c0 = (tid & 31) * 8;
        const float* sp = state + (size_t)(m0 + row) * 256 + c0;
        const float4 a = *(const float4*)sp;
        const float4 b = *(const float4*)(sp + 4);
        union { unsigned short us[8]; short8 v; } pk;
        pk.us[0] = f2bf(a.x); pk.us[1] = f2bf(a.y); pk.us[2] = f2bf(a.z); pk.us[3] = f2bf(a.w);
        pk.us[4] = f2bf(b.x); pk.us[5] = f2bf(b.y); pk.us[6] = f2bf(b.z); pk.us[7] = f2bf(b.w);
        *(short8*)(hbuf0 + row * HSTR + c0) = pk.v;
    }
    // c^0
    float cc[8];
#pragma unroll
    for (int h = 0; h < 2; ++h)
#pragma unroll
        for (int r = 0; r < 4; ++r)
            cc[h * 4 + r] = state[(size_t)(m0 + q * 4 + r) * 256 + (h ? u1 : u0)];

    __syncthreads();

    unsigned short* hcur = hbuf0;
    unsigned short* hnxt = hbuf1;
    f32x4 accA[4], accB[4];
    const float* zbw = zf32 + (size_t)lane * 4 + (size_t)w * 2048;

    // prologue: z(0) both halves straight into acc
    {
        const float* zb = zbw + (size_t)m * 16384;
#pragma unroll
        for (int g = 0; g < 4; ++g) {
            accA[g] = *(const f32x4*)(zb + g * 256);
            accB[g] = *(const f32x4*)(zb + 1024 + g * 256);
        }
    }

    for (int s = 0; s < NSTEP; ++s) {
        const bool last = (s == NSTEP - 1);
        const unsigned short* hrow = hcur + cid * HSTR + q * 8;
        const float* zbn = zbw + ((size_t)(s + 1) * 32 + m) * 16384;

        // half 0: tiles 0..3 resident; C-in = accA (z preloaded)
        __builtin_amdgcn_s_setprio(1);
#pragma unroll
        for (int kk = 0; kk < 8; ++kk) {
            const short8 a = *(const short8*)(hrow + kk * 32);
            accA[0] = __builtin_amdgcn_mfma_f32_16x16x32_bf16(a, Wres[0][kk], accA[0], 0, 0, 0);
            accA[1] = __builtin_amdgcn_mfma_f32_16x16x32_bf16(a, Wres[1][kk], accA[1], 0, 0, 0);
            accA[2] = __builtin_amdgcn_mfma_f32_16x16x32_bf16(a, Wres[2][kk], accA[2], 0, 0, 0);
            accA[3] = __builtin_amdgcn_mfma_f32_16x16x32_bf16(a, Wres[3][kk], accA[3], 0, 0, 0);
        }
        __builtin_amdgcn_s_setprio(0);

        // gates half 0 (consume accA)
#pragma unroll
        for (int r = 0; r < 4; ++r) {
            const float c = sigm(accA[1][r]) * cc[r] + sigm(accA[0][r]) * tanh_(accA[2][r]);
            cc[r] = c;
            const float hv = sigm(accA[3][r]) * tanh_(c);
            if (!last) hnxt[(q * 4 + r) * HSTR + u0] = f2bf(hv);
            else       hfing[(size_t)(m0 + q * 4 + r) * 256 + u0] = hv;
        }

        // accA dead: reload with z(s+1) half-0
        if (!last) {
#pragma unroll
            for (int g = 0; g < 4; ++g)
                accA[g] = *(const f32x4*)(zbn + g * 256);
        }

        // half 1: tiles 4,5 resident + 6,7 LDS; C-in = accB
        __builtin_amdgcn_s_setprio(1);
#pragma unroll
        for (int kk = 0; kk < 8; ++kk) {
            const short8 a = *(const short8*)(hrow + kk * 32);
            accB[0] = __builtin_amdgcn_mfma_f32_16x16x32_bf16(a, Wres[4][kk], accB[0], 0, 0, 0);
            accB[1] = __builtin_amdgcn_mfma_f32_16x16x32_bf16(a, Wres[5][kk], accB[1], 0, 0, 0);
            const short8 b6 = *(const short8*)(ldsW + (((w * 2 + 0) * 8 + kk) * 64 + lane) * 8);
            accB[2] = __builtin_amdgcn_mfma_f32_16x16x32_bf16(a, b6, accB[2], 0, 0, 0);
            const short8 b7 = *(const short8*)(ldsW + (((w * 2 + 1) * 8 + kk) * 64 + lane) * 8);
            accB[3] = __builtin_amdgcn_mfma_f32_16x16x32_bf16(a, b7, accB[3], 0, 0, 0);
        }
        __builtin_amdgcn_s_setprio(0);

        // gates half 1 (consume accB)
#pragma unroll
        for (int r = 0; r < 4; ++r) {
            const float c = sigm(accB[1][r]) * cc[4 + r] + sigm(accB[0][r]) * tanh_(accB[2][r]);
            cc[4 + r] = c;
            const float hv = sigm(accB[3][r]) * tanh_(c);
            if (!last) hnxt[(q * 4 + r) * HSTR + u1] = f2bf(hv);
            else       hfing[(size_t)(m0 + q * 4 + r) * 256 + u1] = hv;
        }

        // accB dead: reload with z(s+1) half-1
        if (!last) {
#pragma unroll
            for (int g = 0; g < 4; ++g)
                accB[g] = *(const f32x4*)(zbn + 1024 + g * 256);
        }

        // lgkm-only barrier: h-exchange needs LDS visibility ONLY.
        asm volatile("s_waitcnt lgkmcnt(0)" ::: "memory");
        __builtin_amdgcn_s_barrier();

        { unsigned short* t_ = hcur; hcur = hnxt; hnxt = t_; }
    }

    __syncthreads();   // drain before head

    // head: out = relu(h_final @ Wo + bo)
    float* redL = (float*)smem;
    if (tid < 256) {
        const int row = tid >> 4, c16 = tid & 15;
        float part = 0.0f;
#pragma unroll
        for (int j = 0; j < 16; ++j) {
            const int u = c16 + j * 16;
            part += hfing[(size_t)(m0 + row) * 256 + u] * Wo[u];
        }
        redL[row * 16 + c16] = part;
    }
    __syncthreads();
    if (tid < 16) {
        float sum = 0.0f;
#pragma unroll
        for (int j = 0; j < 16; ++j) sum += redL[tid * 16 + j];
        out[m0 + tid] = fmaxf(sum + bo_p[0], 0.0f);
    }
}

// ---------------------------------------------------------------------------
// Fallback: r7 fused producer/consumer kernel (used when ws can't hold the
// full 255-step ring). Verified at 1464 us.
// ---------------------------------------------------------------------------
__global__ __launch_bounds__(512, 1)
void fused_kernel(const float* __restrict__ hist, const float* __restrict__ act,
                  const float* __restrict__ state,
                  const unsigned short* __restrict__ W2k, const unsigned short* __restrict__ W2r,
                  const float* __restrict__ blr2,
                  const float* __restrict__ Wo, const float* __restrict__ bo_p,
                  float* __restrict__ zf32, float* __restrict__ hfing,
                  unsigned int* __restrict__ prod_flag, unsigned int* __restrict__ cons_prog,
                  float* __restrict__ out,
                  int WSH, int NW, int RS, int ring_steps)
{
    __shared__ __align__(16) unsigned char smem[148992];
    unsigned short* ldsW = (unsigned short*)smem;
    unsigned short* hbuf0 = (unsigned short*)(smem + 131072);
    unsigned short* hbuf1 = (unsigned short*)(smem + 140032);

    const int tid = threadIdx.x;
    const int w = tid >> 6, lane = tid & 63, q = lane >> 4, cid = lane & 15;
    const int bx = blockIdx.x;
    const int WIN = 1 << WSH, WMASK = WIN - 1;

    if (bx < 32) {
        const int m = bx, m0 = m * 16;
        const int u0 = (w >> 1) * 64 + ((w & 1) * 2 + 0) * 16 + cid;
        const int u1 = u0 + 16;

        short8 Wres[6][8];
#pragma unroll
        for (int t = 0; t < 6; ++t) {
#pragma unroll
            for (int kk = 0; kk < 8; ++kk)
                Wres[t][kk] = *(const short8*)(W2r + ((size_t)((w * 8 + t) * 8 + kk) * 64 + lane) * 8);
        }
#pragma unroll
        for (int tt = 0; tt < 2; ++tt) {
#pragma unroll
            for (int kk = 0; kk < 8; ++kk) {
                short8 f = *(const short8*)(W2r + ((size_t)((w * 8 + 6 + tt) * 8 + kk) * 64 + lane) * 8);
                *(short8*)(ldsW + (((w * 2 + tt) * 8 + kk) * 64 + lane) * 8) = f;
            }
        }
        {
            const int row = tid >> 5, c0 = (tid & 31) * 8;
            const float* sp = state + (size_t)(m0 + row) * 256 + c0;
            const float4 a = *(const float4*)sp;
            const float4 b = *(const float4*)(sp + 4);
            union { unsigned short us[8]; short8 v; } pk;
            pk.us[0] = f2bf(a.x); pk.us[1] = f2bf(a.y); pk.us[2] = f2bf(a.z); pk.us[3] = f2bf(a.w);
            pk.us[4] = f2bf(b.x); pk.us[5] = f2bf(b.y); pk.us[6] = f2bf(b.z); pk.us[7] = f2bf(b.w);
            *(short8*)(hbuf0 + row * HSTR + c0) = pk.v;
        }
        float cc[8];
#pragma unroll
        for (int h = 0; h < 2; ++h)
#pragma unroll
            for (int r = 0; r < 4; ++r)
                cc[h * 4 + r] = state[(size_t)(m0 + q * 4 + r) * 256 + (h ? u1 : u0)];

        __syncthreads();

        unsigned short* hcur = hbuf0;
        unsigned short* hnxt = hbuf1;
        int zslot = 0;
        f32x4 accA[4], accB[4];
        const float* zbw = zf32 + (size_t)lane * 4 + (size_t)w * 2048;

        while (__hip_atomic_load(&prod_flag[m * 4],
                                 __ATOMIC_ACQUIRE, __HIP_MEMORY_SCOPE_AGENT) == 0)
            __builtin_amdgcn_s_sleep(1);
        {
            const float* zb = zbw + (size_t)m * 16384;
#pragma unroll
            for (int g = 0; g < 4; ++g) {
                accA[g] = *(const f32x4*)(zb + g * 256);
                accB[g] = *(const f32x4*)(zb + 1024 + g * 256);
            }
        }

        for (int s = 0; s < NSTEP; ++s) {
            const bool last = (s == NSTEP - 1);

            if (RS < 2 && s > 0) {
                if ((s & WMASK) == 0) {
                    const int f = s >> WSH;
                    while (__hip_atomic_load(&prod_flag[(f * 32 + m) * 4],
                                             __ATOMIC_ACQUIRE, __HIP_MEMORY_SCOPE_AGENT) == 0)
                        __builtin_amdgcn_s_sleep(1);
                }
                const float* zb = zbw + ((size_t)zslot * 32 + m) * 16384;
#pragma unroll
                for (int g = 0; g < 4; ++g) {
                    accA[g] = *(const f32x4*)(zb + g * 256);
                    accB[g] = *(const f32x4*)(zb + 1024 + g * 256);
                }
            }

            const unsigned short* hrow = hcur + cid * HSTR + q * 8;
            const int znext = (zslot + 1 == ring_steps) ? 0 : zslot + 1;

            __builtin_amdgcn_s_setprio(1);
#pragma unroll
            for (int kk = 0; kk < 8; ++kk) {
                const short8 a = *(const short8*)(hrow + kk * 32);
                accA[0] = __builtin_amdgcn_mfma_f32_16x16x32_bf16(a, Wres[0][kk], accA[0], 0, 0, 0);
                accA[1] = __builtin_amdgcn_mfma_f32_16x16x32_bf16(a, Wres[1][kk], accA[1], 0, 0, 0);
                accA[2] = __builtin_amdgcn_mfma_f32_16x16x32_bf16(a, Wres[2][kk], accA[2], 0, 0, 0);
                accA[3] = __builtin_amdgcn_mfma_f32_16x16x32_bf16(a, Wres[3][kk], accA[3], 0, 0, 0);
            }
            __builtin_amdgcn_s_setprio(0);

#pragma unroll
            for (int r = 0; r < 4; ++r) {
                const float c = sigm(accA[1][r]) * cc[r] + sigm(accA[0][r]) * tanh_(accA[2][r]);
                cc[r] = c;
                const float hv = sigm(accA[3][r]) * tanh_(c);
                if (!last) hnxt[(q * 4 + r) * HSTR + u0] = f2bf(hv);
                else       hfing[(size_t)(m0 + q * 4 + r) * 256 + u0] = hv;
            }

            if (!last && RS >= 2) {
                if (((s + 1) & WMASK) == 0) {
                    const int fn = (s + 1) >> WSH;
                    while (__hip_atomic_load(&prod_flag[(fn * 32 + m) * 4],
                                             __ATOMIC_ACQUIRE, __HIP_MEMORY_SCOPE_AGENT) == 0)
                        __builtin_amdgcn_s_sleep(1);
                }
                const float* zbn = zbw + ((size_t)znext * 32 + m) * 16384;
#pragma unroll
                for (int g = 0; g < 4; ++g)
                    accA[g] = *(const f32x4*)(zbn + g * 256);
            }

            __builtin_amdgcn_s_setprio(1);
#pragma unroll
            for (int kk = 0; kk < 8; ++kk) {
                const short8 a = *(const short8*)(hrow + kk * 32);
                accB[0] = __builtin_amdgcn_mfma_f32_16x16x32_bf16(a, Wres[4][kk], accB[0], 0, 0, 0);
                accB[1] = __builtin_amdgcn_mfma_f32_16x16x32_bf16(a, Wres[5][kk], accB[1], 0, 0, 0);
                const short8 b6 = *(const short8*)(ldsW + (((w * 2 + 0) * 8 + kk) * 64 + lane) * 8);
                accB[2] = __builtin_amdgcn_mfma_f32_16x16x32_bf16(a, b6, accB[2], 0, 0, 0);
                const short8 b7 = *(const short8*)(ldsW + (((w * 2 + 1) * 8 + kk) * 64 + lane) * 8);
                accB[3] = __builtin_amdgcn_mfma_f32_16x16x32_bf16(a, b7, accB[3], 0, 0, 0);
            }
            __builtin_amdgcn_s_setprio(0);

#pragma unroll
            for (int r = 0; r < 4; ++r) {
                const float c = sigm(accB[1][r]) * cc[4 + r] + sigm(accB[0][r]) * tanh_(accB[2][r]);
                cc[4 + r] = c;
                const float hv = sigm(accB[3][r]) * tanh_(c);
                if (!last) hnxt[(q * 4 + r) * HSTR + u1] = f2bf(hv);
                else       hfing[(size_t)(m0 + q * 4 + r) * 256 + u1] = hv;
            }

            if (!last && RS >= 2) {
                const float* zbn = zbw + ((size_t)znext * 32 + m) * 16384;
#pragma unroll
                for (int g = 0; g < 4; ++g)
                    accB[g] = *(const f32x4*)(zbn + 1024 + g * 256);
            }

            asm volatile("s_waitcnt lgkmcnt(0)" ::: "memory");
            __builtin_amdgcn_s_barrier();

            { unsigned short* t_ = hcur; hcur = hnxt; hnxt = t_; }
            if (((s + 1) & WMASK) == 0 && tid == 0)
                __hip_atomic_store(&cons_prog[m * 16], (unsigned)((s + 1) >> WSH),
                                   __ATOMIC_RELEASE, __HIP_MEMORY_SCOPE_AGENT);
            zslot = znext;
        }

        __syncthreads();

        float* redL = (float*)smem;
        if (tid < 256) {
            const int row = tid >> 4, c16 = tid & 15;
            float part = 0.0f;
#pragma unroll
            for (int j = 0; j < 16; ++j) {
                const int u = c16 + j * 16;
                part += hfing[(size_t)(m0 + row) * 256 + u] * Wo[u];
            }
            redL[row * 16 + c16] = part;
        }
        __syncthreads();
        if (tid < 16) {
            float sum = 0.0f;
#pragma unroll
            for (int j = 0; j < 16; ++j) sum += redL[tid * 16 + j];
            out[m0 + tid] = fmaxf(sum + bo_p[0], 0.0f);
        }
    } else {
        const int p = bx - 32;
        const int total = NW * 32;
        const int slot0 = w & 3, tchalf = w >> 2;
        for (int tau = p; tau < total; tau += 224) {
            const int w_ = tau >> 5, m = tau & 31, m0 = m * 16;
            const int nst = (WIN < NSTEP - w_ * WIN) ? WIN : (NSTEP - w_ * WIN);
            if (w_ >= RS) {
                const unsigned need = (unsigned)(w_ - RS + 1);
                while (__hip_atomic_load(&cons_prog[m * 16],
                                         __ATOMIC_ACQUIRE, __HIP_MEMORY_SCOPE_AGENT) < need)
                    __builtin_amdgcn_s_sleep(4);
            }
            int ns_my = 0; int sabs[2] = {0, 0};
            for (int sl = slot0; sl < nst; sl += 4) { if (ns_my < 2) sabs[ns_my++] = w_ * WIN + sl; }

            short8 A2[2][8];
#pragma unroll
            for (int si = 0; si < 2; ++si) {
                if (si < ns_my) {
                    const int s = sabs[si];
                    const float* xs = (s < 127)
                        ? hist + ((size_t)(m0 + cid) * 128 + s) * 256
                        : act + ((size_t)(m0 + cid) * 128 + (s - 127)) * 256;
#pragma unroll
                    for (int kk = 0; kk < 8; ++kk) {
                        const float4 a = *(const float4*)(xs + kk * 32 + q * 8);
                        const float4 b = *(const float4*)(xs + kk * 32 + q * 8 + 4);
                        union { unsigned short us[8]; short8 v; } pk;
                        pk.us[0] = f2bf(a.x); pk.us[1] = f2bf(a.y);
                        pk.us[2] = f2bf(a.z); pk.us[3] = f2bf(a.w);
                        pk.us[4] = f2bf(b.x); pk.us[5] = f2bf(b.y);
                        pk.us[6] = f2bf(b.z); pk.us[7] = f2bf(b.w);
                        A2[si][kk] = pk.v;
                    }
                }
            }
            if (ns_my > 0) {
                for (int Tc = tchalf * 8; Tc < tchalf * 8 + 8; ++Tc) {
                    float bias[4];
#pragma unroll
                    for (int t = 0; t < 4; ++t) bias[t] = blr2[(Tc * 4 + t) * 64 + lane];
                    f32x4 acc[2][4];
#pragma unroll
                    for (int si = 0; si < 2; ++si)
#pragma unroll
                        for (int t = 0; t < 4; ++t)
                            acc[si][t] = (f32x4){bias[t], bias[t], bias[t], bias[t]};
#pragma unroll
                    for (int kk = 0; kk < 8; ++kk) {
                        short8 Wf[4];
#pragma unroll
                        for (int t = 0; t < 4; ++t)
                            Wf[t] = *(const short8*)(W2k + ((size_t)((Tc * 4 + t) * 8 + kk) * 64 + lane) * 8);
#pragma unroll
                        for (int t = 0; t < 4; ++t) {
                            acc[0][t] = __builtin_amdgcn_mfma_f32_16x16x32_bf16(A2[0][kk], Wf[t], acc[0][t], 0, 0, 0);
                            if (ns_my > 1)
                                acc[1][t] = __builtin_amdgcn_mfma_f32_16x16x32_bf16(A2[1][kk], Wf[t], acc[1][t], 0, 0, 0);
                        }
                    }
#pragma unroll
                    for (int si = 0; si < 2; ++si) {
                        if (si < ns_my) {
                            const int zsl = sabs[si] % ring_steps;
                            float* zo_ = zf32 + ((size_t)zsl * 32 + m) * 16384 + (size_t)lane * 4;
#pragma unroll
                            for (int t = 0; t < 4; ++t)
                                *(f32x4*)(zo_ + (Tc * 4 + t) * 256) = acc[si][t];
                        }
                    }
                }
            }
            __syncthreads();
            if (tid == 0)
                __hip_atomic_store(&prod_flag[(w_ * 32 + m) * 4], 1u,
                                   __ATOMIC_RELEASE, __HIP_MEMORY_SCOPE_AGENT);
        }
    }
}

// ---------------------------------------------------------------------------
extern "C" void kernel_launch(void* const* d_in, const int* in_sizes, int n_in,
                              void* d_out, int out_size, void* d_ws, size_t ws_size,
                              hipStream_t stream)
{
    const float* motion = (const float*)d_in[0];
    const float* robot  = (const float*)d_in[1];
    const float* osr    = (const float*)d_in[2];
    const float* osi    = (const float*)d_in[3];
    const float* hist   = (const float*)d_in[4];
    const float* act    = (const float*)d_in[5];
    const float* ore    = (const float*)d_in[6];
    const float* oie    = (const float*)d_in[7];
    const float* Wm  = (const float*)d_in[8];  const float* bm  = (const float*)d_in[9];
    const float* Wr  = (const float*)d_in[10]; const float* br  = (const float*)d_in[11];
    const float* Wre = (const float*)d_in[12]; const float* bre = (const float*)d_in[13];
    const float* Wim = (const float*)d_in[14]; const float* bim = (const float*)d_in[15];
    const float* Wc  = (const float*)d_in[16]; const float* bc  = (const float*)d_in[17];
    const float* Wk  = (const float*)d_in[18];
    const float* Wrk = (const float*)d_in[19];
    const float* bl  = (const float*)d_in[20];
    const float* Wo  = (const float*)d_in[21]; const float* bo  = (const float*)d_in[22];

    char* ws = (char*)d_ws;
    float*          state     = (float*)(ws + 0);                  // 524288
    unsigned short* W2k       = (unsigned short*)(ws + 524288);    // 524288
    unsigned short* W2r       = (unsigned short*)(ws + 1048576);   // 524288
    float*          blr2      = (float*)(ws + 1572864);            // 16384
    unsigned int*   prod_flag = (unsigned int*)(ws + 1589248);     // 163840
    unsigned int*   cons_prog = (unsigned int*)(ws + 1753088);     // 2048
    float*          hfing     = (float*)(ws + 1755136);            // 524288
    float*          zf32      = (float*)(ws + 2279424);            // f32 ring
    float*          out       = (float*)d_out;

    size_t avail = (ws_size > 2279424) ? ws_size - 2279424 : 0;
    long rs_max = (long)(avail / 2097152);   // capacity in steps

    encoder_kernel<<<dim3(32), dim3(256), 0, stream>>>(
        motion, robot, osr, osi, ore, oie,
        Wm, bm, Wr, br, Wre, bre, Wim, bim, Wc, bc, state);
    prep_kernel<<<dim3(257), dim3(256), 0, stream>>>(
        Wk, Wrk, bl, W2k, W2r, blr2, prod_flag, cons_prog);

    if (rs_max >= NSTEP) {
        // clean split: full ring, no handshake
        zgemm_kernel<<<dim3(512), dim3(512), 0, stream>>>(hist, act, W2k, blr2, zf32);
        recur_kernel<<<dim3(32), dim3(512), 0, stream>>>(state, W2r, Wo, bo, zf32, hfing, out);
    } else {
        // fallback: r7 fused producer/consumer
        int WIN = 1, NW = 255, RS = 1;
        const int wins[4] = {8, 4, 2, 1};
        for (int i = 0; i < 4; ++i) {
            const int Wn = wins[i];
            const int nw = (NSTEP + Wn - 1) / Wn;
            long rs = rs_max / Wn; if (rs > nw) rs = nw;
            if (rs >= 2) { WIN = Wn; NW = nw; RS = (int)rs; break; }
            if (Wn == 1) { WIN = 1; NW = nw; RS = (int)(rs >= 1 ? rs : 1); }
        }
        int ring_steps = RS * WIN; if (ring_steps < 1) ring_steps = 1;
        const int WSH = (WIN == 8) ? 3 : (WIN == 4) ? 2 : (WIN == 2) ? 1 : 0;
        fused_kernel<<<dim3(256), dim3(512), 0, stream>>>(
            hist, act, state, W2k, W2r, blr2, Wo, bo,
            zf32, hfing, prod_flag, cons_prog, out, WSH, NW, RS, ring_steps);
    }
}

// Round 9
// 1354.048 us; speedup vs baseline: 3.1185x; 1.2909x over previous
//
#include <hip/hip_runtime.h>
#include <stdint.h>

// ---------------------------------------------------------------------------
// Critic: encoder -> 255-step LSTM (U=256, D_in=256) -> 1-unit relu head. B=512
//
// Round-12 design (r7 fused structure + bf16 z ring):
//  - z ring stored as PACKED bf16 C-fragments (u64 = 4 values/tile/lane):
//    halves z HBM write traffic (510->255 MB) and makes the ring
//    ~L3-resident (read latency ~300cy not ~900cy).
//  - Consumer loads z(s+1) as 4 x 16B per wave at the TOP of step s and
//    unpacks into accumulators at the top of step s+1 -> a FULL step of
//    latency cover (r7's in-place reload had only ~half a step).
//  - bf16 z is accuracy-verified: rounds 0-2 used bf16 z, absmax 0.0039.
//  - Everything else identical to r7 (1464 us): __launch_bounds__(512,1),
//    6 reg + 2 LDS Wrk tiles/wave, lgkm-only barrier, window handshake.
// ---------------------------------------------------------------------------

#define NSTEP 255

typedef __attribute__((ext_vector_type(8))) short short8;   // 8 x bf16
typedef __attribute__((ext_vector_type(4))) float f32x4;
typedef unsigned long long u64t;

#define HSTR 280   // hbuf row stride in shorts (560 B, 16B-aligned)

__device__ __forceinline__ unsigned short f2bf(float f) {
    union { float f; unsigned int u; } v; v.f = f;
    unsigned int r = v.u + 0x7FFFu + ((v.u >> 16) & 1u);   // RNE
    return (unsigned short)(r >> 16);
}
__device__ __forceinline__ float bf2f(unsigned short u) {
    union { float f; unsigned int v; } x; x.v = ((unsigned int)u) << 16; return x.f;
}
__device__ __forceinline__ u64t pack4(const f32x4 v) {
    return (u64t)f2bf(v[0]) | ((u64t)f2bf(v[1]) << 16)
         | ((u64t)f2bf(v[2]) << 32) | ((u64t)f2bf(v[3]) << 48);
}
__device__ __forceinline__ float fexp2(float x) { return __builtin_amdgcn_exp2f(x); }
__device__ __forceinline__ float frcp(float x)  { return __builtin_amdgcn_rcpf(x); }
__device__ __forceinline__ float sigm(float x)  { return frcp(1.0f + fexp2(-1.44269504f * x)); }
__device__ __forceinline__ float tanh_(float x) { return 1.0f - 2.0f * frcp(1.0f + fexp2(2.88539008f * x)); }

// ---------------------------------------------------------------------------
// Encoder: state = relu(concat(ms,rs,re,im) @ Wc + bc)   [512,256] fp32
// ---------------------------------------------------------------------------
__global__ __launch_bounds__(256)
void encoder_kernel(const float* __restrict__ motion, const float* __restrict__ robot,
                    const float* __restrict__ osr, const float* __restrict__ osi,
                    const float* __restrict__ ore, const float* __restrict__ oie,
                    const float* __restrict__ Wm, const float* __restrict__ bm,
                    const float* __restrict__ Wr, const float* __restrict__ br,
                    const float* __restrict__ Wre, const float* __restrict__ bre,
                    const float* __restrict__ Wim, const float* __restrict__ bim,
                    const float* __restrict__ Wc, const float* __restrict__ bc,
                    float* __restrict__ state)
{
    __shared__ float in_m[16][64];
    __shared__ float in_r[16][128];
    __shared__ float in_re[16][128];
    __shared__ float in_im[16][128];
    __shared__ float catb[16 * 768];
    const int t = threadIdx.x;
    const int m0 = blockIdx.x * 16;

    {
        int idx = t * 4; int row = idx >> 6, col = idx & 63;
        *(float4*)&in_m[row][col]       = *(const float4*)(motion + (m0 + row) * 64 + col);
        *(float4*)&in_re[row][col]      = *(const float4*)(osr + (m0 + row) * 64 + col);
        *(float4*)&in_re[row][64 + col] = *(const float4*)(ore + (m0 + row) * 64 + col);
        *(float4*)&in_im[row][col]      = *(const float4*)(osi + (m0 + row) * 64 + col);
        *(float4*)&in_im[row][64 + col] = *(const float4*)(oie + (m0 + row) * 64 + col);
    }
    for (int p = 0; p < 2; ++p) {
        int idx = (t + p * 256) * 4; int row = idx >> 7, col = idx & 127;
        *(float4*)&in_r[row][col] = *(const float4*)(robot + (m0 + row) * 128 + col);
    }
    __syncthreads();

    for (int row = 0; row < 16; ++row) {
        {
            float s = bm[t];
            for (int k = 0; k < 64; ++k) s += in_m[row][k] * Wm[k * 256 + t];
            catb[row * 768 + t] = fmaxf(s, 0.0f);
        }
        {
            float s = br[t];
            for (int k = 0; k < 128; ++k) s += in_r[row][k] * Wr[k * 256 + t];
            catb[row * 768 + 256 + t] = fmaxf(s, 0.0f);
        }
        if (t < 128) {
            float s = bre[t];
            for (int k = 0; k < 128; ++k) s += in_re[row][k] * Wre[k * 128 + t];
            catb[row * 768 + 512 + t] = fmaxf(s, 0.0f);
        } else {
            const int u = t - 128;
            float s = bim[u];
            for (int k = 0; k < 128; ++k) s += in_im[row][k] * Wim[k * 128 + u];
            catb[row * 768 + 640 + u] = fmaxf(s, 0.0f);
        }
    }
    __syncthreads();

    for (int r0 = 0; r0 < 16; r0 += 4) {
        float a0 = bc[t], a1 = bc[t], a2 = bc[t], a3 = bc[t];
        for (int j = 0; j < 768; ++j) {
            const float wv = Wc[j * 256 + t];
            a0 += catb[(r0 + 0) * 768 + j] * wv;
            a1 += catb[(r0 + 1) * 768 + j] * wv;
            a2 += catb[(r0 + 2) * 768 + j] * wv;
            a3 += catb[(r0 + 3) * 768 + j] * wv;
        }
        state[(m0 + r0 + 0) * 256 + t] = fmaxf(a0, 0.0f);
        state[(m0 + r0 + 1) * 256 + t] = fmaxf(a1, 0.0f);
        state[(m0 + r0 + 2) * 256 + t] = fmaxf(a2, 0.0f);
        state[(m0 + r0 + 3) * 256 + t] = fmaxf(a3, 0.0f);
    }
}

// ---------------------------------------------------------------------------
// Prep: W2k/W2r in frag-linear layout [(T*8+kk)*64+lane][8], bf16.
// ---------------------------------------------------------------------------
__global__ __launch_bounds__(256)
void prep_kernel(const float* __restrict__ Wk, const float* __restrict__ Wrk,
                 const float* __restrict__ bl,
                 unsigned short* __restrict__ W2k, unsigned short* __restrict__ W2r,
                 float* __restrict__ blr2,
                 unsigned int* __restrict__ prod_flag, unsigned int* __restrict__ cons_prog)
{
    const int blk = blockIdx.x, t = threadIdx.x;
    if (blk < 256) {
        const int mat = blk >> 7;
        const int idx = (blk & 127) * 256 + t;      // (T*8+kk)*64+lane
        const int T = idx >> 9, kk = (idx >> 6) & 7, lane = idx & 63;
        const int q = lane >> 4, cid = lane & 15;
        const int wv = T >> 4, gam = (T >> 2) & 3, g = T & 3;
        const int col = g * 256 + wv * 64 + gam * 16 + cid;
        const float* W = mat ? Wrk : Wk;
        unsigned short* O = mat ? W2r : W2k;
#pragma unroll
        for (int j = 0; j < 8; ++j) {
            const int k = kk * 32 + q * 8 + j;
            O[(size_t)idx * 8 + j] = f2bf(W[(size_t)k * 1024 + col]);
        }
    } else {
        for (int e = t; e < 4096; e += 256) {
            const int T = e >> 6, lane = e & 63, cid = lane & 15;
            const int wv = T >> 4, gam = (T >> 2) & 3, g = T & 3;
            blr2[e] = bl[g * 256 + wv * 64 + gam * 16 + cid];
        }
        for (int i = t; i < 40960; i += 256) prod_flag[i] = 0u;
        for (int i = t; i < 512; i += 256) cons_prog[i] = 0u;
    }
}

// ---------------------------------------------------------------------------
// Fused: blocks 0..31 = consumers (recurrence, 8 waves), 32..255 = producers.
// z ring: PACKED bf16. Per (slot, m): 4096 u64; pair P (=T/2) at
//   zq[(slot*32+m)*4096 + (P*64+lane)*2]  as ulonglong2 {tile 2P, tile 2P+1},
//   each u64 = 4 bf16 (r=0..3).
// ---------------------------------------------------------------------------
__global__ __launch_bounds__(512, 1)
void fused_kernel(const float* __restrict__ hist, const float* __restrict__ act,
                  const float* __restrict__ state,
                  const unsigned short* __restrict__ W2k, const unsigned short* __restrict__ W2r,
                  const float* __restrict__ blr2,
                  const float* __restrict__ Wo, const float* __restrict__ bo_p,
                  u64t* __restrict__ zq, float* __restrict__ hfing,
                  unsigned int* __restrict__ prod_flag, unsigned int* __restrict__ cons_prog,
                  float* __restrict__ out,
                  int WSH, int NW, int RS, int ring_steps)
{
    __shared__ __align__(16) unsigned char smem[148992];
    unsigned short* ldsW = (unsigned short*)smem;
    unsigned short* hbuf0 = (unsigned short*)(smem + 131072);
    unsigned short* hbuf1 = (unsigned short*)(smem + 140032);

    const int tid = threadIdx.x;
    const int w = tid >> 6, lane = tid & 63, q = lane >> 4, cid = lane & 15;
    const int bx = blockIdx.x;
    const int WIN = 1 << WSH, WMASK = WIN - 1;

    if (bx < 32) {
        // ======================= CONSUMER =======================
        const int m = bx, m0 = m * 16;
        const int u0 = (w >> 1) * 64 + ((w & 1) * 2 + 0) * 16 + cid;
        const int u1 = u0 + 16;

        short8 Wres[6][8];
#pragma unroll
        for (int t = 0; t < 6; ++t) {
#pragma unroll
            for (int kk = 0; kk < 8; ++kk)
                Wres[t][kk] = *(const short8*)(W2r + ((size_t)((w * 8 + t) * 8 + kk) * 64 + lane) * 8);
        }
#pragma unroll
        for (int tt = 0; tt < 2; ++tt) {
#pragma unroll
            for (int kk = 0; kk < 8; ++kk) {
                short8 f = *(const short8*)(W2r + ((size_t)((w * 8 + 6 + tt) * 8 + kk) * 64 + lane) * 8);
                *(short8*)(ldsW + (((w * 2 + tt) * 8 + kk) * 64 + lane) * 8) = f;
            }
        }
        {
            const int row = tid >> 5, c0 = (tid & 31) * 8;
            const float* sp = state + (size_t)(m0 + row) * 256 + c0;
            const float4 a = *(const float4*)sp;
            const float4 b = *(const float4*)(sp + 4);
            union { unsigned short us[8]; short8 v; } pk;
            pk.us[0] = f2bf(a.x); pk.us[1] = f2bf(a.y); pk.us[2] = f2bf(a.z); pk.us[3] = f2bf(a.w);
            pk.us[4] = f2bf(b.x); pk.us[5] = f2bf(b.y); pk.us[6] = f2bf(b.z); pk.us[7] = f2bf(b.w);
            *(short8*)(hbuf0 + row * HSTR + c0) = pk.v;
        }
        float cc[8];
#pragma unroll
        for (int h = 0; h < 2; ++h)
#pragma unroll
            for (int r = 0; r < 4; ++r)
                cc[h * 4 + r] = state[(size_t)(m0 + q * 4 + r) * 256 + (h ? u1 : u0)];

        __syncthreads();

        unsigned short* hcur = hbuf0;
        unsigned short* hnxt = hbuf1;
        int zslot = 0;
        ulonglong2 zc[4];                 // packed z for CURRENT step (16 regs)
        // wave's pair base offset (u64 units): pairs P = w*4 .. w*4+3
        const size_t zoff = ((size_t)(w * 4) * 64 + lane) * 2;

        // prologue: window 0 acquire + z(0) packed load
        while (__hip_atomic_load(&prod_flag[m * 4],
                                 __ATOMIC_ACQUIRE, __HIP_MEMORY_SCOPE_AGENT) == 0)
            __builtin_amdgcn_s_sleep(1);
        {
            const u64t* zb = zq + (size_t)m * 4096 + zoff;
            zc[0] = *(const ulonglong2*)(zb + 0);
            zc[1] = *(const ulonglong2*)(zb + 128);
            zc[2] = *(const ulonglong2*)(zb + 256);
            zc[3] = *(const ulonglong2*)(zb + 384);
        }

        for (int s = 0; s < NSTEP; ++s) {
            const bool last = (s == NSTEP - 1);

            // legacy path (RS<2): synchronous packed load each step
            if (RS < 2 && s > 0) {
                if ((s & WMASK) == 0) {
                    const int f = s >> WSH;
                    while (__hip_atomic_load(&prod_flag[(f * 32 + m) * 4],
                                             __ATOMIC_ACQUIRE, __HIP_MEMORY_SCOPE_AGENT) == 0)
                        __builtin_amdgcn_s_sleep(1);
                }
                const u64t* zb = zq + ((size_t)zslot * 32 + m) * 4096 + zoff;
                zc[0] = *(const ulonglong2*)(zb + 0);
                zc[1] = *(const ulonglong2*)(zb + 128);
                zc[2] = *(const ulonglong2*)(zb + 256);
                zc[3] = *(const ulonglong2*)(zb + 384);
            }

            // ---- top of step: unpack zc -> accA/accB (waitcnt lands here,
            //      a full step after the loads were issued) ----
            f32x4 accA[4], accB[4];
#pragma unroll
            for (int j = 0; j < 4; ++j) {
                const u64t v = (j & 1) ? zc[j >> 1].y : zc[j >> 1].x;
#pragma unroll
                for (int r = 0; r < 4; ++r)
                    accA[j][r] = bf2f((unsigned short)(v >> (16 * r)));
            }
#pragma unroll
            for (int j = 0; j < 4; ++j) {
                const u64t v = (j & 1) ? zc[(j >> 1) + 2].y : zc[(j >> 1) + 2].x;
#pragma unroll
                for (int r = 0; r < 4; ++r)
                    accB[j][r] = bf2f((unsigned short)(v >> (16 * r)));
            }

            // ---- issue z(s+1) packed loads NOW (full-step cover) ----
            const int znext = (zslot + 1 == ring_steps) ? 0 : zslot + 1;
            if (!last && RS >= 2) {
                if (((s + 1) & WMASK) == 0) {
                    const int fn = (s + 1) >> WSH;
                    while (__hip_atomic_load(&prod_flag[(fn * 32 + m) * 4],
                                             __ATOMIC_ACQUIRE, __HIP_MEMORY_SCOPE_AGENT) == 0)
                        __builtin_amdgcn_s_sleep(1);
                }
                const u64t* zb = zq + ((size_t)znext * 32 + m) * 4096 + zoff;
                zc[0] = *(const ulonglong2*)(zb + 0);
                zc[1] = *(const ulonglong2*)(zb + 128);
                zc[2] = *(const ulonglong2*)(zb + 256);
                zc[3] = *(const ulonglong2*)(zb + 384);
            }

            const unsigned short* hrow = hcur + cid * HSTR + q * 8;

            // half 0: tiles 0..3 register-resident
            __builtin_amdgcn_s_setprio(1);
#pragma unroll
            for (int kk = 0; kk < 8; ++kk) {
                const short8 a = *(const short8*)(hrow + kk * 32);
                accA[0] = __builtin_amdgcn_mfma_f32_16x16x32_bf16(a, Wres[0][kk], accA[0], 0, 0, 0);
                accA[1] = __builtin_amdgcn_mfma_f32_16x16x32_bf16(a, Wres[1][kk], accA[1], 0, 0, 0);
                accA[2] = __builtin_amdgcn_mfma_f32_16x16x32_bf16(a, Wres[2][kk], accA[2], 0, 0, 0);
                accA[3] = __builtin_amdgcn_mfma_f32_16x16x32_bf16(a, Wres[3][kk], accA[3], 0, 0, 0);
            }
            __builtin_amdgcn_s_setprio(0);

            // gates half 0
#pragma unroll
            for (int r = 0; r < 4; ++r) {
                const float c = sigm(accA[1][r]) * cc[r] + sigm(accA[0][r]) * tanh_(accA[2][r]);
                cc[r] = c;
                const float hv = sigm(accA[3][r]) * tanh_(c);
                if (!last) hnxt[(q * 4 + r) * HSTR + u0] = f2bf(hv);
                else       hfing[(size_t)(m0 + q * 4 + r) * 256 + u0] = hv;
            }

            // half 1: tiles 4,5 resident + 6,7 LDS
            __builtin_amdgcn_s_setprio(1);
#pragma unroll
            for (int kk = 0; kk < 8; ++kk) {
                const short8 a = *(const short8*)(hrow + kk * 32);
                accB[0] = __builtin_amdgcn_mfma_f32_16x16x32_bf16(a, Wres[4][kk], accB[0], 0, 0, 0);
                accB[1] = __builtin_amdgcn_mfma_f32_16x16x32_bf16(a, Wres[5][kk], accB[1], 0, 0, 0);
                const short8 b6 = *(const short8*)(ldsW + (((w * 2 + 0) * 8 + kk) * 64 + lane) * 8);
                accB[2] = __builtin_amdgcn_mfma_f32_16x16x32_bf16(a, b6, accB[2], 0, 0, 0);
                const short8 b7 = *(const short8*)(ldsW + (((w * 2 + 1) * 8 + kk) * 64 + lane) * 8);
                accB[3] = __builtin_amdgcn_mfma_f32_16x16x32_bf16(a, b7, accB[3], 0, 0, 0);
            }
            __builtin_amdgcn_s_setprio(0);

            // gates half 1
#pragma unroll
            for (int r = 0; r < 4; ++r) {
                const float c = sigm(accB[1][r]) * cc[4 + r] + sigm(accB[0][r]) * tanh_(accB[2][r]);
                cc[4 + r] = c;
                const float hv = sigm(accB[3][r]) * tanh_(c);
                if (!last) hnxt[(q * 4 + r) * HSTR + u1] = f2bf(hv);
                else       hfing[(size_t)(m0 + q * 4 + r) * 256 + u1] = hv;
            }

            // lgkm-only barrier: h-exchange needs LDS visibility ONLY.
            asm volatile("s_waitcnt lgkmcnt(0)" ::: "memory");
            __builtin_amdgcn_s_barrier();

            { unsigned short* t_ = hcur; hcur = hnxt; hnxt = t_; }
            if (((s + 1) & WMASK) == 0 && tid == 0)
                __hip_atomic_store(&cons_prog[m * 16], (unsigned)((s + 1) >> WSH),
                                   __ATOMIC_RELEASE, __HIP_MEMORY_SCOPE_AGENT);
            zslot = znext;
        }

        __syncthreads();   // full drain before head

        // head: out = relu(h_final @ Wo + bo)
        float* redL = (float*)smem;
        if (tid < 256) {
            const int row = tid >> 4, c16 = tid & 15;
            float part = 0.0f;
#pragma unroll
            for (int j = 0; j < 16; ++j) {
                const int u = c16 + j * 16;
                part += hfing[(size_t)(m0 + row) * 256 + u] * Wo[u];
            }
            redL[row * 16 + c16] = part;
        }
        __syncthreads();
        if (tid < 16) {
            float sum = 0.0f;
#pragma unroll
            for (int j = 0; j < 16; ++j) sum += redL[tid * 16 + j];
            out[m0 + tid] = fmaxf(sum + bo_p[0], 0.0f);
        }
    } else {
        // ======================= PRODUCER =======================
        const int p = bx - 32;
        const int total = NW * 32;
        const int slot0 = w & 3, tchalf = w >> 2;   // 4 step-slots x 2 Tc halves
        for (int tau = p; tau < total; tau += 224) {
            const int w_ = tau >> 5, m = tau & 31, m0 = m * 16;
            const int nst = (WIN < NSTEP - w_ * WIN) ? WIN : (NSTEP - w_ * WIN);
            if (w_ >= RS) {
                const unsigned need = (unsigned)(w_ - RS + 1);
                while (__hip_atomic_load(&cons_prog[m * 16],
                                         __ATOMIC_ACQUIRE, __HIP_MEMORY_SCOPE_AGENT) < need)
                    __builtin_amdgcn_s_sleep(4);
            }
            int ns_my = 0; int sabs[2] = {0, 0};
            for (int sl = slot0; sl < nst; sl += 4) { if (ns_my < 2) sabs[ns_my++] = w_ * WIN + sl; }

            short8 A2[2][8];
#pragma unroll
            for (int si = 0; si < 2; ++si) {
                if (si < ns_my) {
                    const int s = sabs[si];
                    const float* xs = (s < 127)
                        ? hist + ((size_t)(m0 + cid) * 128 + s) * 256
                        : act + ((size_t)(m0 + cid) * 128 + (s - 127)) * 256;
#pragma unroll
                    for (int kk = 0; kk < 8; ++kk) {
                        const float4 a = *(const float4*)(xs + kk * 32 + q * 8);
                        const float4 b = *(const float4*)(xs + kk * 32 + q * 8 + 4);
                        union { unsigned short us[8]; short8 v; } pk;
                        pk.us[0] = f2bf(a.x); pk.us[1] = f2bf(a.y);
                        pk.us[2] = f2bf(a.z); pk.us[3] = f2bf(a.w);
                        pk.us[4] = f2bf(b.x); pk.us[5] = f2bf(b.y);
                        pk.us[6] = f2bf(b.z); pk.us[7] = f2bf(b.w);
                        A2[si][kk] = pk.v;
                    }
                }
            }
            if (ns_my > 0) {
                for (int Tc = tchalf * 8; Tc < tchalf * 8 + 8; ++Tc) {
                    float bias[4];
#pragma unroll
                    for (int t = 0; t < 4; ++t) bias[t] = blr2[(Tc * 4 + t) * 64 + lane];
                    f32x4 acc[2][4];
#pragma unroll
                    for (int si = 0; si < 2; ++si)
#pragma unroll
                        for (int t = 0; t < 4; ++t)
                            acc[si][t] = (f32x4){bias[t], bias[t], bias[t], bias[t]};
#pragma unroll
                    for (int kk = 0; kk < 8; ++kk) {
                        short8 Wf[4];
#pragma unroll
                        for (int t = 0; t < 4; ++t)
                            Wf[t] = *(const short8*)(W2k + ((size_t)((Tc * 4 + t) * 8 + kk) * 64 + lane) * 8);
#pragma unroll
                        for (int t = 0; t < 4; ++t) {
                            acc[0][t] = __builtin_amdgcn_mfma_f32_16x16x32_bf16(A2[0][kk], Wf[t], acc[0][t], 0, 0, 0);
                            if (ns_my > 1)
                                acc[1][t] = __builtin_amdgcn_mfma_f32_16x16x32_bf16(A2[1][kk], Wf[t], acc[1][t], 0, 0, 0);
                        }
                    }
#pragma unroll
                    for (int si = 0; si < 2; ++si) {
                        if (si < ns_my) {
                            const int zsl = sabs[si] % ring_steps;
                            u64t* zb = zq + ((size_t)zsl * 32 + m) * 4096;
                            ulonglong2 v0, v1;
                            v0.x = pack4(acc[si][0]); v0.y = pack4(acc[si][1]);
                            v1.x = pack4(acc[si][2]); v1.y = pack4(acc[si][3]);
                            *(ulonglong2*)(zb + ((size_t)(Tc * 2 + 0) * 64 + lane) * 2) = v0;
                            *(ulonglong2*)(zb + ((size_t)(Tc * 2 + 1) * 64 + lane) * 2) = v1;
                        }
                    }
                }
            }
            __syncthreads();
            if (tid == 0)
                __hip_atomic_store(&prod_flag[(w_ * 32 + m) * 4], 1u,
                                   __ATOMIC_RELEASE, __HIP_MEMORY_SCOPE_AGENT);
        }
    }
}

// ---------------------------------------------------------------------------
extern "C" void kernel_launch(void* const* d_in, const int* in_sizes, int n_in,
                              void* d_out, int out_size, void* d_ws, size_t ws_size,
                              hipStream_t stream)
{
    const float* motion = (const float*)d_in[0];
    const float* robot  = (const float*)d_in[1];
    const float* osr    = (const float*)d_in[2];
    const float* osi    = (const float*)d_in[3];
    const float* hist   = (const float*)d_in[4];
    const float* act    = (const float*)d_in[5];
    const float* ore    = (const float*)d_in[6];
    const float* oie    = (const float*)d_in[7];
    const float* Wm  = (const float*)d_in[8];  const float* bm  = (const float*)d_in[9];
    const float* Wr  = (const float*)d_in[10]; const float* br  = (const float*)d_in[11];
    const float* Wre = (const float*)d_in[12]; const float* bre = (const float*)d_in[13];
    const float* Wim = (const float*)d_in[14]; const float* bim = (const float*)d_in[15];
    const float* Wc  = (const float*)d_in[16]; const float* bc  = (const float*)d_in[17];
    const float* Wk  = (const float*)d_in[18];
    const float* Wrk = (const float*)d_in[19];
    const float* bl  = (const float*)d_in[20];
    const float* Wo  = (const float*)d_in[21]; const float* bo  = (const float*)d_in[22];

    char* ws = (char*)d_ws;
    float*          state     = (float*)(ws + 0);                  // 524288
    unsigned short* W2k       = (unsigned short*)(ws + 524288);    // 524288
    unsigned short* W2r       = (unsigned short*)(ws + 1048576);   // 524288
    float*          blr2      = (float*)(ws + 1572864);            // 16384
    unsigned int*   prod_flag = (unsigned int*)(ws + 1589248);     // 163840
    unsigned int*   cons_prog = (unsigned int*)(ws + 1753088);     // 2048
    float*          hfing     = (float*)(ws + 1755136);            // 524288
    u64t*           zq        = (u64t*)(ws + 2279424);             // packed bf16 ring
    float*          out       = (float*)d_out;

    // adaptive ring: per-step z is now 1 MB (32 tiles x 32 KB packed bf16).
    size_t avail = (ws_size > 2279424) ? ws_size - 2279424 : 0;
    long rs_max = (long)(avail / 1048576);
    int WIN = 1, NW = 255, RS = 1;
    const int wins[4] = {8, 4, 2, 1};
    for (int i = 0; i < 4; ++i) {
        const int Wn = wins[i];
        const int nw = (NSTEP + Wn - 1) / Wn;
        long rs = rs_max / Wn; if (rs > nw) rs = nw;
        if (rs >= 2) { WIN = Wn; NW = nw; RS = (int)rs; break; }
        if (Wn == 1) { WIN = 1; NW = nw; RS = (int)(rs >= 1 ? rs : 1); }
    }
    int ring_steps = RS * WIN; if (ring_steps < 1) ring_steps = 1;
    const int WSH = (WIN == 8) ? 3 : (WIN == 4) ? 2 : (WIN == 2) ? 1 : 0;

    encoder_kernel<<<dim3(32), dim3(256), 0, stream>>>(
        motion, robot, osr, osi, ore, oie,
        Wm, bm, Wr, br, Wre, bre, Wim, bim, Wc, bc, state);
    prep_kernel<<<dim3(257), dim3(256), 0, stream>>>(
        Wk, Wrk, bl, W2k, W2r, blr2, prod_flag, cons_prog);
    fused_kernel<<<dim3(256), dim3(512), 0, stream>>>(
        hist, act, state, W2k, W2r, blr2, Wo, bo,
        zq, hfing, prod_flag, cons_prog, out, WSH, NW, RS, ring_steps);
}

// Round 10
// 1353.609 us; speedup vs baseline: 3.1195x; 1.0003x over previous
//
#include <hip/hip_runtime.h>
#include <stdint.h>

// ---------------------------------------------------------------------------
// Critic: encoder -> 255-step LSTM (U=256, D_in=256) -> 1-unit relu head. B=512
//
// Round-13 design:
//  - bf16 packed z ring (r9, verified) shrinks the full-sequence ring to
//    267 MB -> the r8 clean SPLIT now fits the workspace:
//      zgemm_kernel: all 255 steps of z = x@Wk + bl on 512 blocks (pure
//        GEMM, all CUs, no flags), packed bf16 stores.
//      recur_kernel: 32 blocks, recurrence ONLY -- zero atomics, zero
//        spins, no producer interference; z slot = step index.
//    Fallback (ws too small): exact r9 fused kernel (verified 1069 us).
//  - encoder+prep merged into ONE dispatch (independent work, 289 blocks)
//    to remove launch serialization.
// ---------------------------------------------------------------------------

#define NSTEP 255

typedef __attribute__((ext_vector_type(8))) short short8;   // 8 x bf16
typedef __attribute__((ext_vector_type(4))) float f32x4;
typedef unsigned long long u64t;

#define HSTR 280   // hbuf row stride in shorts (560 B, 16B-aligned)

__device__ __forceinline__ unsigned short f2bf(float f) {
    union { float f; unsigned int u; } v; v.f = f;
    unsigned int r = v.u + 0x7FFFu + ((v.u >> 16) & 1u);   // RNE
    return (unsigned short)(r >> 16);
}
__device__ __forceinline__ float bf2f(unsigned short u) {
    union { float f; unsigned int v; } x; x.v = ((unsigned int)u) << 16; return x.f;
}
__device__ __forceinline__ u64t pack4(const f32x4 v) {
    return (u64t)f2bf(v[0]) | ((u64t)f2bf(v[1]) << 16)
         | ((u64t)f2bf(v[2]) << 32) | ((u64t)f2bf(v[3]) << 48);
}
__device__ __forceinline__ float fexp2(float x) { return __builtin_amdgcn_exp2f(x); }
__device__ __forceinline__ float frcp(float x)  { return __builtin_amdgcn_rcpf(x); }
__device__ __forceinline__ float sigm(float x)  { return frcp(1.0f + fexp2(-1.44269504f * x)); }
__device__ __forceinline__ float tanh_(float x) { return 1.0f - 2.0f * frcp(1.0f + fexp2(2.88539008f * x)); }

// ---------------------------------------------------------------------------
// Merged encoder + prep (independent work, one dispatch):
//   blocks 0..31   : encoder (state = relu(concat @ Wc + bc))
//   blocks 32..287 : W2k/W2r frag-linear bf16 conversion
//   block  288     : blr2 + flag init
// ---------------------------------------------------------------------------
__global__ __launch_bounds__(256)
void encprep_kernel(const float* __restrict__ motion, const float* __restrict__ robot,
                    const float* __restrict__ osr, const float* __restrict__ osi,
                    const float* __restrict__ ore, const float* __restrict__ oie,
                    const float* __restrict__ Wm, const float* __restrict__ bm,
                    const float* __restrict__ Wr, const float* __restrict__ br,
                    const float* __restrict__ Wre, const float* __restrict__ bre,
                    const float* __restrict__ Wim, const float* __restrict__ bim,
                    const float* __restrict__ Wc, const float* __restrict__ bc,
                    const float* __restrict__ Wk, const float* __restrict__ Wrk,
                    const float* __restrict__ bl,
                    unsigned short* __restrict__ W2k, unsigned short* __restrict__ W2r,
                    float* __restrict__ blr2,
                    unsigned int* __restrict__ prod_flag, unsigned int* __restrict__ cons_prog,
                    float* __restrict__ state)
{
    const int t = threadIdx.x;
    if (blockIdx.x >= 32) {
        const int blk = blockIdx.x - 32;
        if (blk < 256) {
            const int mat = blk >> 7;
            const int idx = (blk & 127) * 256 + t;      // (T*8+kk)*64+lane
            const int T = idx >> 9, kk = (idx >> 6) & 7, lane = idx & 63;
            const int q = lane >> 4, cid = lane & 15;
            const int wv = T >> 4, gam = (T >> 2) & 3, g = T & 3;
            const int col = g * 256 + wv * 64 + gam * 16 + cid;
            const float* W = mat ? Wrk : Wk;
            unsigned short* O = mat ? W2r : W2k;
#pragma unroll
            for (int j = 0; j < 8; ++j) {
                const int k = kk * 32 + q * 8 + j;
                O[(size_t)idx * 8 + j] = f2bf(W[(size_t)k * 1024 + col]);
            }
        } else {
            for (int e = t; e < 4096; e += 256) {
                const int T = e >> 6, lane = e & 63, cid = lane & 15;
                const int wv = T >> 4, gam = (T >> 2) & 3, g = T & 3;
                blr2[e] = bl[g * 256 + wv * 64 + gam * 16 + cid];
            }
            for (int i = t; i < 40960; i += 256) prod_flag[i] = 0u;
            for (int i = t; i < 512; i += 256) cons_prog[i] = 0u;
        }
        return;
    }

    // -------- encoder role --------
    __shared__ float in_m[16][64];
    __shared__ float in_r[16][128];
    __shared__ float in_re[16][128];
    __shared__ float in_im[16][128];
    __shared__ float catb[16 * 768];
    const int m0 = blockIdx.x * 16;

    {
        int idx = t * 4; int row = idx >> 6, col = idx & 63;
        *(float4*)&in_m[row][col]       = *(const float4*)(motion + (m0 + row) * 64 + col);
        *(float4*)&in_re[row][col]      = *(const float4*)(osr + (m0 + row) * 64 + col);
        *(float4*)&in_re[row][64 + col] = *(const float4*)(ore + (m0 + row) * 64 + col);
        *(float4*)&in_im[row][col]      = *(const float4*)(osi + (m0 + row) * 64 + col);
        *(float4*)&in_im[row][64 + col] = *(const float4*)(oie + (m0 + row) * 64 + col);
    }
    for (int p = 0; p < 2; ++p) {
        int idx = (t + p * 256) * 4; int row = idx >> 7, col = idx & 127;
        *(float4*)&in_r[row][col] = *(const float4*)(robot + (m0 + row) * 128 + col);
    }
    __syncthreads();

    for (int row = 0; row < 16; ++row) {
        {
            float s = bm[t];
            for (int k = 0; k < 64; ++k) s += in_m[row][k] * Wm[k * 256 + t];
            catb[row * 768 + t] = fmaxf(s, 0.0f);
        }
        {
            float s = br[t];
            for (int k = 0; k < 128; ++k) s += in_r[row][k] * Wr[k * 256 + t];
            catb[row * 768 + 256 + t] = fmaxf(s, 0.0f);
        }
        if (t < 128) {
            float s = bre[t];
            for (int k = 0; k < 128; ++k) s += in_re[row][k] * Wre[k * 128 + t];
            catb[row * 768 + 512 + t] = fmaxf(s, 0.0f);
        } else {
            const int u = t - 128;
            float s = bim[u];
            for (int k = 0; k < 128; ++k) s += in_im[row][k] * Wim[k * 128 + u];
            catb[row * 768 + 640 + u] = fmaxf(s, 0.0f);
        }
    }
    __syncthreads();

    for (int r0 = 0; r0 < 16; r0 += 4) {
        float a0 = bc[t], a1 = bc[t], a2 = bc[t], a3 = bc[t];
        for (int j = 0; j < 768; ++j) {
            const float wv = Wc[j * 256 + t];
            a0 += catb[(r0 + 0) * 768 + j] * wv;
            a1 += catb[(r0 + 1) * 768 + j] * wv;
            a2 += catb[(r0 + 2) * 768 + j] * wv;
            a3 += catb[(r0 + 3) * 768 + j] * wv;
        }
        state[(m0 + r0 + 0) * 256 + t] = fmaxf(a0, 0.0f);
        state[(m0 + r0 + 1) * 256 + t] = fmaxf(a1, 0.0f);
        state[(m0 + r0 + 2) * 256 + t] = fmaxf(a2, 0.0f);
        state[(m0 + r0 + 3) * 256 + t] = fmaxf(a3, 0.0f);
    }
}

// ---------------------------------------------------------------------------
// Phase A (split mode): z[s] = x_s @ Wk + bl for ALL 255 steps, packed bf16.
// 512 blocks x 8 waves (4 step-slots x 2 Tc halves). No flags, no gating.
// ---------------------------------------------------------------------------
__global__ __launch_bounds__(512, 2)
void zgemm_kernel(const float* __restrict__ hist, const float* __restrict__ act,
                  const unsigned short* __restrict__ W2k, const float* __restrict__ blr2,
                  u64t* __restrict__ zq)
{
    const int tid = threadIdx.x;
    const int w = tid >> 6, lane = tid & 63, q = lane >> 4, cid = lane & 15;
    const int slot0 = w & 3, tchalf = w >> 2;
    const int total = 32 * 32;   // 32 windows (WIN=8) x 32 tiles

    for (int tau = blockIdx.x; tau < total; tau += 512) {
        const int w_ = tau >> 5, m = tau & 31, m0 = m * 16;
        const int nst = (8 < NSTEP - w_ * 8) ? 8 : (NSTEP - w_ * 8);
        int ns_my = 0; int sabs[2] = {0, 0};
        for (int sl = slot0; sl < nst; sl += 4) { if (ns_my < 2) sabs[ns_my++] = w_ * 8 + sl; }
        if (ns_my == 0) continue;

        short8 A2[2][8];
#pragma unroll
        for (int si = 0; si < 2; ++si) {
            if (si < ns_my) {
                const int s = sabs[si];
                const float* xs = (s < 127)
                    ? hist + ((size_t)(m0 + cid) * 128 + s) * 256
                    : act + ((size_t)(m0 + cid) * 128 + (s - 127)) * 256;
#pragma unroll
                for (int kk = 0; kk < 8; ++kk) {
                    const float4 a = *(const float4*)(xs + kk * 32 + q * 8);
                    const float4 b = *(const float4*)(xs + kk * 32 + q * 8 + 4);
                    union { unsigned short us[8]; short8 v; } pk;
                    pk.us[0] = f2bf(a.x); pk.us[1] = f2bf(a.y);
                    pk.us[2] = f2bf(a.z); pk.us[3] = f2bf(a.w);
                    pk.us[4] = f2bf(b.x); pk.us[5] = f2bf(b.y);
                    pk.us[6] = f2bf(b.z); pk.us[7] = f2bf(b.w);
                    A2[si][kk] = pk.v;
                }
            }
        }
        for (int Tc = tchalf * 8; Tc < tchalf * 8 + 8; ++Tc) {
            float bias[4];
#pragma unroll
            for (int t = 0; t < 4; ++t) bias[t] = blr2[(Tc * 4 + t) * 64 + lane];
            f32x4 acc[2][4];
#pragma unroll
            for (int si = 0; si < 2; ++si)
#pragma unroll
                for (int t = 0; t < 4; ++t)
                    acc[si][t] = (f32x4){bias[t], bias[t], bias[t], bias[t]};
#pragma unroll
            for (int kk = 0; kk < 8; ++kk) {
                short8 Wf[4];
#pragma unroll
                for (int t = 0; t < 4; ++t)
                    Wf[t] = *(const short8*)(W2k + ((size_t)((Tc * 4 + t) * 8 + kk) * 64 + lane) * 8);
#pragma unroll
                for (int t = 0; t < 4; ++t) {
                    acc[0][t] = __builtin_amdgcn_mfma_f32_16x16x32_bf16(A2[0][kk], Wf[t], acc[0][t], 0, 0, 0);
                    if (ns_my > 1)
                        acc[1][t] = __builtin_amdgcn_mfma_f32_16x16x32_bf16(A2[1][kk], Wf[t], acc[1][t], 0, 0, 0);
                }
            }
#pragma unroll
            for (int si = 0; si < 2; ++si) {
                if (si < ns_my) {
                    u64t* zb = zq + ((size_t)sabs[si] * 32 + m) * 4096;
                    ulonglong2 v0, v1;
                    v0.x = pack4(acc[si][0]); v0.y = pack4(acc[si][1]);
                    v1.x = pack4(acc[si][2]); v1.y = pack4(acc[si][3]);
                    *(ulonglong2*)(zb + ((size_t)(Tc * 2 + 0) * 64 + lane) * 2) = v0;
                    *(ulonglong2*)(zb + ((size_t)(Tc * 2 + 1) * 64 + lane) * 2) = v1;
                }
            }
        }
    }
}

// ---------------------------------------------------------------------------
// Phase B (split mode): recurrence ONLY. 32 blocks x 8 waves.
// No atomics, no spins. z slot = step index. r9 consumer structure.
// ---------------------------------------------------------------------------
__global__ __launch_bounds__(512, 1)
void recur_kernel(const float* __restrict__ state,
                  const unsigned short* __restrict__ W2r,
                  const float* __restrict__ Wo, const float* __restrict__ bo_p,
                  const u64t* __restrict__ zq, float* __restrict__ hfing,
                  float* __restrict__ out)
{
    __shared__ __align__(16) unsigned char smem[148992];
    unsigned short* ldsW = (unsigned short*)smem;
    unsigned short* hbuf0 = (unsigned short*)(smem + 131072);
    unsigned short* hbuf1 = (unsigned short*)(smem + 140032);

    const int tid = threadIdx.x;
    const int w = tid >> 6, lane = tid & 63, q = lane >> 4, cid = lane & 15;
    const int m = blockIdx.x, m0 = m * 16;
    const int u0 = (w >> 1) * 64 + ((w & 1) * 2 + 0) * 16 + cid;
    const int u1 = u0 + 16;

    short8 Wres[6][8];
#pragma unroll
    for (int t = 0; t < 6; ++t) {
#pragma unroll
        for (int kk = 0; kk < 8; ++kk)
            Wres[t][kk] = *(const short8*)(W2r + ((size_t)((w * 8 + t) * 8 + kk) * 64 + lane) * 8);
    }
#pragma unroll
    for (int tt = 0; tt < 2; ++tt) {
#pragma unroll
        for (int kk = 0; kk < 8; ++kk) {
            short8 f = *(const short8*)(W2r + ((size_t)((w * 8 + 6 + tt) * 8 + kk) * 64 + lane) * 8);
            *(short8*)(ldsW + (((w * 2 + tt) * 8 + kk) * 64 + lane) * 8) = f;
        }
    }
    {
        const int row = tid >> 5, c0 = (tid & 31) * 8;
        const float* sp = state + (size_t)(m0 + row) * 256 + c0;
        const float4 a = *(const float4*)sp;
        const float4 b = *(const float4*)(sp + 4);
        union { unsigned short us[8]; short8 v; } pk;
        pk.us[0] = f2bf(a.x); pk.us[1] = f2bf(a.y); pk.us[2] = f2bf(a.z); pk.us[3] = f2bf(a.w);
        pk.us[4] = f2bf(b.x); pk.us[5] = f2bf(b.y); pk.us[6] = f2bf(b.z); pk.us[7] = f2bf(b.w);
        *(short8*)(hbuf0 + row * HSTR + c0) = pk.v;
    }
    float cc[8];
#pragma unroll
    for (int h = 0; h < 2; ++h)
#pragma unroll
        for (int r = 0; r < 4; ++r)
            cc[h * 4 + r] = state[(size_t)(m0 + q * 4 + r) * 256 + (h ? u1 : u0)];

    __syncthreads();

    unsigned short* hcur = hbuf0;
    unsigned short* hnxt = hbuf1;
    ulonglong2 zc[4];
    const size_t zoff = ((size_t)(w * 4) * 64 + lane) * 2;

    {
        const u64t* zb = zq + (size_t)m * 4096 + zoff;
        zc[0] = *(const ulonglong2*)(zb + 0);
        zc[1] = *(const ulonglong2*)(zb + 128);
        zc[2] = *(const ulonglong2*)(zb + 256);
        zc[3] = *(const ulonglong2*)(zb + 384);
    }

    for (int s = 0; s < NSTEP; ++s) {
        const bool last = (s == NSTEP - 1);

        // unpack zc -> acc (waitcnt lands a full step after issue)
        f32x4 accA[4], accB[4];
#pragma unroll
        for (int j = 0; j < 4; ++j) {
            const u64t v = (j & 1) ? zc[j >> 1].y : zc[j >> 1].x;
#pragma unroll
            for (int r = 0; r < 4; ++r)
                accA[j][r] = bf2f((unsigned short)(v >> (16 * r)));
        }
#pragma unroll
        for (int j = 0; j < 4; ++j) {
            const u64t v = (j & 1) ? zc[(j >> 1) + 2].y : zc[(j >> 1) + 2].x;
#pragma unroll
            for (int r = 0; r < 4; ++r)
                accB[j][r] = bf2f((unsigned short)(v >> (16 * r)));
        }

        // issue z(s+1) packed loads (full-step cover, no flag check)
        if (!last) {
            const u64t* zb = zq + ((size_t)(s + 1) * 32 + m) * 4096 + zoff;
            zc[0] = *(const ulonglong2*)(zb + 0);
            zc[1] = *(const ulonglong2*)(zb + 128);
            zc[2] = *(const ulonglong2*)(zb + 256);
            zc[3] = *(const ulonglong2*)(zb + 384);
        }

        const unsigned short* hrow = hcur + cid * HSTR + q * 8;

        __builtin_amdgcn_s_setprio(1);
#pragma unroll
        for (int kk = 0; kk < 8; ++kk) {
            const short8 a = *(const short8*)(hrow + kk * 32);
            accA[0] = __builtin_amdgcn_mfma_f32_16x16x32_bf16(a, Wres[0][kk], accA[0], 0, 0, 0);
            accA[1] = __builtin_amdgcn_mfma_f32_16x16x32_bf16(a, Wres[1][kk], accA[1], 0, 0, 0);
            accA[2] = __builtin_amdgcn_mfma_f32_16x16x32_bf16(a, Wres[2][kk], accA[2], 0, 0, 0);
            accA[3] = __builtin_amdgcn_mfma_f32_16x16x32_bf16(a, Wres[3][kk], accA[3], 0, 0, 0);
        }
        __builtin_amdgcn_s_setprio(0);

#pragma unroll
        for (int r = 0; r < 4; ++r) {
            const float c = sigm(accA[1][r]) * cc[r] + sigm(accA[0][r]) * tanh_(accA[2][r]);
            cc[r] = c;
            const float hv = sigm(accA[3][r]) * tanh_(c);
            if (!last) hnxt[(q * 4 + r) * HSTR + u0] = f2bf(hv);
            else       hfing[(size_t)(m0 + q * 4 + r) * 256 + u0] = hv;
        }

        __builtin_amdgcn_s_setprio(1);
#pragma unroll
        for (int kk = 0; kk < 8; ++kk) {
            const short8 a = *(const short8*)(hrow + kk * 32);
            accB[0] = __builtin_amdgcn_mfma_f32_16x16x32_bf16(a, Wres[4][kk], accB[0], 0, 0, 0);
            accB[1] = __builtin_amdgcn_mfma_f32_16x16x32_bf16(a, Wres[5][kk], accB[1], 0, 0, 0);
            const short8 b6 = *(const short8*)(ldsW + (((w * 2 + 0) * 8 + kk) * 64 + lane) * 8);
            accB[2] = __builtin_amdgcn_mfma_f32_16x16x32_bf16(a, b6, accB[2], 0, 0, 0);
            const short8 b7 = *(const short8*)(ldsW + (((w * 2 + 1) * 8 + kk) * 64 + lane) * 8);
            accB[3] = __builtin_amdgcn_mfma_f32_16x16x32_bf16(a, b7, accB[3], 0, 0, 0);
        }
        __builtin_amdgcn_s_setprio(0);

#pragma unroll
        for (int r = 0; r < 4; ++r) {
            const float c = sigm(accB[1][r]) * cc[4 + r] + sigm(accB[0][r]) * tanh_(accB[2][r]);
            cc[4 + r] = c;
            const float hv = sigm(accB[3][r]) * tanh_(c);
            if (!last) hnxt[(q * 4 + r) * HSTR + u1] = f2bf(hv);
            else       hfing[(size_t)(m0 + q * 4 + r) * 256 + u1] = hv;
        }

        asm volatile("s_waitcnt lgkmcnt(0)" ::: "memory");
        __builtin_amdgcn_s_barrier();

        { unsigned short* t_ = hcur; hcur = hnxt; hnxt = t_; }
    }

    __syncthreads();

    float* redL = (float*)smem;
    if (tid < 256) {
        const int row = tid >> 4, c16 = tid & 15;
        float part = 0.0f;
#pragma unroll
        for (int j = 0; j < 16; ++j) {
            const int u = c16 + j * 16;
            part += hfing[(size_t)(m0 + row) * 256 + u] * Wo[u];
        }
        redL[row * 16 + c16] = part;
    }
    __syncthreads();
    if (tid < 16) {
        float sum = 0.0f;
#pragma unroll
        for (int j = 0; j < 16; ++j) sum += redL[tid * 16 + j];
        out[m0 + tid] = fmaxf(sum + bo_p[0], 0.0f);
    }
}

// ---------------------------------------------------------------------------
// Fallback: r9 fused producer/consumer (verified 1069 us fused).
// ---------------------------------------------------------------------------
__global__ __launch_bounds__(512, 1)
void fused_kernel(const float* __restrict__ hist, const float* __restrict__ act,
                  const float* __restrict__ state,
                  const unsigned short* __restrict__ W2k, const unsigned short* __restrict__ W2r,
                  const float* __restrict__ blr2,
                  const float* __restrict__ Wo, const float* __restrict__ bo_p,
                  u64t* __restrict__ zq, float* __restrict__ hfing,
                  unsigned int* __restrict__ prod_flag, unsigned int* __restrict__ cons_prog,
                  float* __restrict__ out,
                  int WSH, int NW, int RS, int ring_steps)
{
    __shared__ __align__(16) unsigned char smem[148992];
    unsigned short* ldsW = (unsigned short*)smem;
    unsigned short* hbuf0 = (unsigned short*)(smem + 131072);
    unsigned short* hbuf1 = (unsigned short*)(smem + 140032);

    const int tid = threadIdx.x;
    const int w = tid >> 6, lane = tid & 63, q = lane >> 4, cid = lane & 15;
    const int bx = blockIdx.x;
    const int WIN = 1 << WSH, WMASK = WIN - 1;

    if (bx < 32) {
        const int m = bx, m0 = m * 16;
        const int u0 = (w >> 1) * 64 + ((w & 1) * 2 + 0) * 16 + cid;
        const int u1 = u0 + 16;

        short8 Wres[6][8];
#pragma unroll
        for (int t = 0; t < 6; ++t) {
#pragma unroll
            for (int kk = 0; kk < 8; ++kk)
                Wres[t][kk] = *(const short8*)(W2r + ((size_t)((w * 8 + t) * 8 + kk) * 64 + lane) * 8);
        }
#pragma unroll
        for (int tt = 0; tt < 2; ++tt) {
#pragma unroll
            for (int kk = 0; kk < 8; ++kk) {
                short8 f = *(const short8*)(W2r + ((size_t)((w * 8 + 6 + tt) * 8 + kk) * 64 + lane) * 8);
                *(short8*)(ldsW + (((w * 2 + tt) * 8 + kk) * 64 + lane) * 8) = f;
            }
        }
        {
            const int row = tid >> 5, c0 = (tid & 31) * 8;
            const float* sp = state + (size_t)(m0 + row) * 256 + c0;
            const float4 a = *(const float4*)sp;
            const float4 b = *(const float4*)(sp + 4);
            union { unsigned short us[8]; short8 v; } pk;
            pk.us[0] = f2bf(a.x); pk.us[1] = f2bf(a.y); pk.us[2] = f2bf(a.z); pk.us[3] = f2bf(a.w);
            pk.us[4] = f2bf(b.x); pk.us[5] = f2bf(b.y); pk.us[6] = f2bf(b.z); pk.us[7] = f2bf(b.w);
            *(short8*)(hbuf0 + row * HSTR + c0) = pk.v;
        }
        float cc[8];
#pragma unroll
        for (int h = 0; h < 2; ++h)
#pragma unroll
            for (int r = 0; r < 4; ++r)
                cc[h * 4 + r] = state[(size_t)(m0 + q * 4 + r) * 256 + (h ? u1 : u0)];

        __syncthreads();

        unsigned short* hcur = hbuf0;
        unsigned short* hnxt = hbuf1;
        int zslot = 0;
        ulonglong2 zc[4];
        const size_t zoff = ((size_t)(w * 4) * 64 + lane) * 2;

        while (__hip_atomic_load(&prod_flag[m * 4],
                                 __ATOMIC_ACQUIRE, __HIP_MEMORY_SCOPE_AGENT) == 0)
            __builtin_amdgcn_s_sleep(1);
        {
            const u64t* zb = zq + (size_t)m * 4096 + zoff;
            zc[0] = *(const ulonglong2*)(zb + 0);
            zc[1] = *(const ulonglong2*)(zb + 128);
            zc[2] = *(const ulonglong2*)(zb + 256);
            zc[3] = *(const ulonglong2*)(zb + 384);
        }

        for (int s = 0; s < NSTEP; ++s) {
            const bool last = (s == NSTEP - 1);

            if (RS < 2 && s > 0) {
                if ((s & WMASK) == 0) {
                    const int f = s >> WSH;
                    while (__hip_atomic_load(&prod_flag[(f * 32 + m) * 4],
                                             __ATOMIC_ACQUIRE, __HIP_MEMORY_SCOPE_AGENT) == 0)
                        __builtin_amdgcn_s_sleep(1);
                }
                const u64t* zb = zq + ((size_t)zslot * 32 + m) * 4096 + zoff;
                zc[0] = *(const ulonglong2*)(zb + 0);
                zc[1] = *(const ulonglong2*)(zb + 128);
                zc[2] = *(const ulonglong2*)(zb + 256);
                zc[3] = *(const ulonglong2*)(zb + 384);
            }

            f32x4 accA[4], accB[4];
#pragma unroll
            for (int j = 0; j < 4; ++j) {
                const u64t v = (j & 1) ? zc[j >> 1].y : zc[j >> 1].x;
#pragma unroll
                for (int r = 0; r < 4; ++r)
                    accA[j][r] = bf2f((unsigned short)(v >> (16 * r)));
            }
#pragma unroll
            for (int j = 0; j < 4; ++j) {
                const u64t v = (j & 1) ? zc[(j >> 1) + 2].y : zc[(j >> 1) + 2].x;
#pragma unroll
                for (int r = 0; r < 4; ++r)
                    accB[j][r] = bf2f((unsigned short)(v >> (16 * r)));
            }

            const int znext = (zslot + 1 == ring_steps) ? 0 : zslot + 1;
            if (!last && RS >= 2) {
                if (((s + 1) & WMASK) == 0) {
                    const int fn = (s + 1) >> WSH;
                    while (__hip_atomic_load(&prod_flag[(fn * 32 + m) * 4],
                                             __ATOMIC_ACQUIRE, __HIP_MEMORY_SCOPE_AGENT) == 0)
                        __builtin_amdgcn_s_sleep(1);
                }
                const u64t* zb = zq + ((size_t)znext * 32 + m) * 4096 + zoff;
                zc[0] = *(const ulonglong2*)(zb + 0);
                zc[1] = *(const ulonglong2*)(zb + 128);
                zc[2] = *(const ulonglong2*)(zb + 256);
                zc[3] = *(const ulonglong2*)(zb + 384);
            }

            const unsigned short* hrow = hcur + cid * HSTR + q * 8;

            __builtin_amdgcn_s_setprio(1);
#pragma unroll
            for (int kk = 0; kk < 8; ++kk) {
                const short8 a = *(const short8*)(hrow + kk * 32);
                accA[0] = __builtin_amdgcn_mfma_f32_16x16x32_bf16(a, Wres[0][kk], accA[0], 0, 0, 0);
                accA[1] = __builtin_amdgcn_mfma_f32_16x16x32_bf16(a, Wres[1][kk], accA[1], 0, 0, 0);
                accA[2] = __builtin_amdgcn_mfma_f32_16x16x32_bf16(a, Wres[2][kk], accA[2], 0, 0, 0);
                accA[3] = __builtin_amdgcn_mfma_f32_16x16x32_bf16(a, Wres[3][kk], accA[3], 0, 0, 0);
            }
            __builtin_amdgcn_s_setprio(0);

#pragma unroll
            for (int r = 0; r < 4; ++r) {
                const float c = sigm(accA[1][r]) * cc[r] + sigm(accA[0][r]) * tanh_(accA[2][r]);
                cc[r] = c;
                const float hv = sigm(accA[3][r]) * tanh_(c);
                if (!last) hnxt[(q * 4 + r) * HSTR + u0] = f2bf(hv);
                else       hfing[(size_t)(m0 + q * 4 + r) * 256 + u0] = hv;
            }

            __builtin_amdgcn_s_setprio(1);
#pragma unroll
            for (int kk = 0; kk < 8; ++kk) {
                const short8 a = *(const short8*)(hrow + kk * 32);
                accB[0] = __builtin_amdgcn_mfma_f32_16x16x32_bf16(a, Wres[4][kk], accB[0], 0, 0, 0);
                accB[1] = __builtin_amdgcn_mfma_f32_16x16x32_bf16(a, Wres[5][kk], accB[1], 0, 0, 0);
                const short8 b6 = *(const short8*)(ldsW + (((w * 2 + 0) * 8 + kk) * 64 + lane) * 8);
                accB[2] = __builtin_amdgcn_mfma_f32_16x16x32_bf16(a, b6, accB[2], 0, 0, 0);
                const short8 b7 = *(const short8*)(ldsW + (((w * 2 + 1) * 8 + kk) * 64 + lane) * 8);
                accB[3] = __builtin_amdgcn_mfma_f32_16x16x32_bf16(a, b7, accB[3], 0, 0, 0);
            }
            __builtin_amdgcn_s_setprio(0);

#pragma unroll
            for (int r = 0; r < 4; ++r) {
                const float c = sigm(accB[1][r]) * cc[4 + r] + sigm(accB[0][r]) * tanh_(accB[2][r]);
                cc[4 + r] = c;
                const float hv = sigm(accB[3][r]) * tanh_(c);
                if (!last) hnxt[(q * 4 + r) * HSTR + u1] = f2bf(hv);
                else       hfing[(size_t)(m0 + q * 4 + r) * 256 + u1] = hv;
            }

            asm volatile("s_waitcnt lgkmcnt(0)" ::: "memory");
            __builtin_amdgcn_s_barrier();

            { unsigned short* t_ = hcur; hcur = hnxt; hnxt = t_; }
            if (((s + 1) & WMASK) == 0 && tid == 0)
                __hip_atomic_store(&cons_prog[m * 16], (unsigned)((s + 1) >> WSH),
                                   __ATOMIC_RELEASE, __HIP_MEMORY_SCOPE_AGENT);
            zslot = znext;
        }

        __syncthreads();

        float* redL = (float*)smem;
        if (tid < 256) {
            const int row = tid >> 4, c16 = tid & 15;
            float part = 0.0f;
#pragma unroll
            for (int j = 0; j < 16; ++j) {
                const int u = c16 + j * 16;
                part += hfing[(size_t)(m0 + row) * 256 + u] * Wo[u];
            }
            redL[row * 16 + c16] = part;
        }
        __syncthreads();
        if (tid < 16) {
            float sum = 0.0f;
#pragma unroll
            for (int j = 0; j < 16; ++j) sum += redL[tid * 16 + j];
            out[m0 + tid] = fmaxf(sum + bo_p[0], 0.0f);
        }
    } else {
        const int p = bx - 32;
        const int total = NW * 32;
        const int slot0 = w & 3, tchalf = w >> 2;
        for (int tau = p; tau < total; tau += 224) {
            const int w_ = tau >> 5, m = tau & 31, m0 = m * 16;
            const int nst = (WIN < NSTEP - w_ * WIN) ? WIN : (NSTEP - w_ * WIN);
            if (w_ >= RS) {
                const unsigned need = (unsigned)(w_ - RS + 1);
                while (__hip_atomic_load(&cons_prog[m * 16],
                                         __ATOMIC_ACQUIRE, __HIP_MEMORY_SCOPE_AGENT) < need)
                    __builtin_amdgcn_s_sleep(4);
            }
            int ns_my = 0; int sabs[2] = {0, 0};
            for (int sl = slot0; sl < nst; sl += 4) { if (ns_my < 2) sabs[ns_my++] = w_ * WIN + sl; }

            short8 A2[2][8];
#pragma unroll
            for (int si = 0; si < 2; ++si) {
                if (si < ns_my) {
                    const int s = sabs[si];
                    const float* xs = (s < 127)
                        ? hist + ((size_t)(m0 + cid) * 128 + s) * 256
                        : act + ((size_t)(m0 + cid) * 128 + (s - 127)) * 256;
#pragma unroll
                    for (int kk = 0; kk < 8; ++kk) {
                        const float4 a = *(const float4*)(xs + kk * 32 + q * 8);
                        const float4 b = *(const float4*)(xs + kk * 32 + q * 8 + 4);
                        union { unsigned short us[8]; short8 v; } pk;
                        pk.us[0] = f2bf(a.x); pk.us[1] = f2bf(a.y);
                        pk.us[2] = f2bf(a.z); pk.us[3] = f2bf(a.w);
                        pk.us[4] = f2bf(b.x); pk.us[5] = f2bf(b.y);
                        pk.us[6] = f2bf(b.z); pk.us[7] = f2bf(b.w);
                        A2[si][kk] = pk.v;
                    }
                }
            }
            if (ns_my > 0) {
                for (int Tc = tchalf * 8; Tc < tchalf * 8 + 8; ++Tc) {
                    float bias[4];
#pragma unroll
                    for (int t = 0; t < 4; ++t) bias[t] = blr2[(Tc * 4 + t) * 64 + lane];
                    f32x4 acc[2][4];
#pragma unroll
                    for (int si = 0; si < 2; ++si)
#pragma unroll
                        for (int t = 0; t < 4; ++t)
                            acc[si][t] = (f32x4){bias[t], bias[t], bias[t], bias[t]};
#pragma unroll
                    for (int kk = 0; kk < 8; ++kk) {
                        short8 Wf[4];
#pragma unroll
                        for (int t = 0; t < 4; ++t)
                            Wf[t] = *(const short8*)(W2k + ((size_t)((Tc * 4 + t) * 8 + kk) * 64 + lane) * 8);
#pragma unroll
                        for (int t = 0; t < 4; ++t) {
                            acc[0][t] = __builtin_amdgcn_mfma_f32_16x16x32_bf16(A2[0][kk], Wf[t], acc[0][t], 0, 0, 0);
                            if (ns_my > 1)
                                acc[1][t] = __builtin_amdgcn_mfma_f32_16x16x32_bf16(A2[1][kk], Wf[t], acc[1][t], 0, 0, 0);
                        }
                    }
#pragma unroll
                    for (int si = 0; si < 2; ++si) {
                        if (si < ns_my) {
                            const int zsl = sabs[si] % ring_steps;
                            u64t* zb = zq + ((size_t)zsl * 32 + m) * 4096;
                            ulonglong2 v0, v1;
                            v0.x = pack4(acc[si][0]); v0.y = pack4(acc[si][1]);
                            v1.x = pack4(acc[si][2]); v1.y = pack4(acc[si][3]);
                            *(ulonglong2*)(zb + ((size_t)(Tc * 2 + 0) * 64 + lane) * 2) = v0;
                            *(ulonglong2*)(zb + ((size_t)(Tc * 2 + 1) * 64 + lane) * 2) = v1;
                        }
                    }
                }
            }
            __syncthreads();
            if (tid == 0)
                __hip_atomic_store(&prod_flag[(w_ * 32 + m) * 4], 1u,
                                   __ATOMIC_RELEASE, __HIP_MEMORY_SCOPE_AGENT);
        }
    }
}

// ---------------------------------------------------------------------------
extern "C" void kernel_launch(void* const* d_in, const int* in_sizes, int n_in,
                              void* d_out, int out_size, void* d_ws, size_t ws_size,
                              hipStream_t stream)
{
    const float* motion = (const float*)d_in[0];
    const float* robot  = (const float*)d_in[1];
    const float* osr    = (const float*)d_in[2];
    const float* osi    = (const float*)d_in[3];
    const float* hist   = (const float*)d_in[4];
    const float* act    = (const float*)d_in[5];
    const float* ore    = (const float*)d_in[6];
    const float* oie    = (const float*)d_in[7];
    const float* Wm  = (const float*)d_in[8];  const float* bm  = (const float*)d_in[9];
    const float* Wr  = (const float*)d_in[10]; const float* br  = (const float*)d_in[11];
    const float* Wre = (const float*)d_in[12]; const float* bre = (const float*)d_in[13];
    const float* Wim = (const float*)d_in[14]; const float* bim = (const float*)d_in[15];
    const float* Wc  = (const float*)d_in[16]; const float* bc  = (const float*)d_in[17];
    const float* Wk  = (const float*)d_in[18];
    const float* Wrk = (const float*)d_in[19];
    const float* bl  = (const float*)d_in[20];
    const float* Wo  = (const float*)d_in[21]; const float* bo  = (const float*)d_in[22];

    char* ws = (char*)d_ws;
    float*          state     = (float*)(ws + 0);                  // 524288
    unsigned short* W2k       = (unsigned short*)(ws + 524288);    // 524288
    unsigned short* W2r       = (unsigned short*)(ws + 1048576);   // 524288
    float*          blr2      = (float*)(ws + 1572864);            // 16384
    unsigned int*   prod_flag = (unsigned int*)(ws + 1589248);     // 163840
    unsigned int*   cons_prog = (unsigned int*)(ws + 1753088);     // 2048
    float*          hfing     = (float*)(ws + 1755136);            // 524288
    u64t*           zq        = (u64t*)(ws + 2279424);             // packed bf16 ring
    float*          out       = (float*)d_out;

    // ring capacity in steps (1 MB/step packed bf16)
    size_t avail = (ws_size > 2279424) ? ws_size - 2279424 : 0;
    long rs_max = (long)(avail / 1048576);

    encprep_kernel<<<dim3(289), dim3(256), 0, stream>>>(
        motion, robot, osr, osi, ore, oie,
        Wm, bm, Wr, br, Wre, bre, Wim, bim, Wc, bc,
        Wk, Wrk, bl, W2k, W2r, blr2, prod_flag, cons_prog, state);

    if (rs_max >= NSTEP) {
        // clean split: full-sequence ring, zero handshake
        zgemm_kernel<<<dim3(512), dim3(512), 0, stream>>>(hist, act, W2k, blr2, zq);
        recur_kernel<<<dim3(32), dim3(512), 0, stream>>>(state, W2r, Wo, bo, zq, hfing, out);
    } else {
        // fallback: r9 fused producer/consumer (verified)
        int WIN = 1, NW = 255, RS = 1;
        const int wins[4] = {8, 4, 2, 1};
        for (int i = 0; i < 4; ++i) {
            const int Wn = wins[i];
            const int nw = (NSTEP + Wn - 1) / Wn;
            long rs = rs_max / Wn; if (rs > nw) rs = nw;
            if (rs >= 2) { WIN = Wn; NW = nw; RS = (int)rs; break; }
            if (Wn == 1) { WIN = 1; NW = nw; RS = (int)(rs >= 1 ? rs : 1); }
        }
        int ring_steps = RS * WIN; if (ring_steps < 1) ring_steps = 1;
        const int WSH = (WIN == 8) ? 3 : (WIN == 4) ? 2 : (WIN == 2) ? 1 : 0;
        fused_kernel<<<dim3(256), dim3(512), 0, stream>>>(
            hist, act, state, W2k, W2r, blr2, Wo, bo,
            zq, hfing, prod_flag, cons_prog, out, WSH, NW, RS, ring_steps);
    }
}